// Round 1
// baseline (1171.914 us; speedup 1.0000x reference)
//
#include <hip/hip_runtime.h>

// Fused block: RMSNorm -> up GEMM -> causal depthwise conv+SiLU -> gate GEMM
// (SiLU*mul fused epilogue) -> down GEMM -> q/k/v GEMMs -> decay linear
// attention as quadratic masked attention (QK^T with d^(t-s) mask, then SV)
// -> wo GEMM + residual.
//
// All GEMMs: bf16 MFMA 16x16x32, 128x128 block tile, 4 waves of 64x64,
// fp32->bf16 convert during LDS staging.

typedef __bf16 bf16x8 __attribute__((ext_vector_type(8)));
typedef unsigned short u16x8 __attribute__((ext_vector_type(8)));
typedef float f32x4 __attribute__((ext_vector_type(4)));

constexpr int Bb = 4, Ll = 2048, Dd = 1024, DIc = 2048;
constexpr long BLD  = (long)Bb * Ll * Dd;    //  8,388,608 floats
constexpr long BLDI = (long)Bb * Ll * DIc;   // 16,777,216 floats
// ws layout (floats): nrm[BLD] | buf1[BLDI] | buf2[BLDI] | S[B*L*L]
// total = 58,720,256 floats = 235 MB

static __device__ __forceinline__ unsigned short f2bf(float f) {
  unsigned u = __builtin_bit_cast(unsigned, f);
  u += 0x7fffu + ((u >> 16) & 1u);   // round-to-nearest-even
  return (unsigned short)(u >> 16);
}

static __device__ __forceinline__ float silu(float g) {
  return g / (1.f + __expf(-g));
}

enum { EPI_NONE = 0, EPI_BIAS = 1, EPI_GATE = 2, EPI_DECAY = 3, EPI_RESID = 4 };

// C = A[M,K] @ B[K,N] (+epilogue). TRANSB: B stored [N,K] row-major.
// All of M%128==0, N%128==0, K%32==0 hold for every call site.
template <int EPI, bool TRANSB>
__global__ __launch_bounds__(256) void gemm_k(
    const float* __restrict__ A, const float* __restrict__ Bm,
    float* __restrict__ C, const float* __restrict__ bias,
    const float* __restrict__ aux, const float* __restrict__ decayp,
    int M, int N, int K, int lda, int ldb, int ldc,
    long sA, long sB, long sC) {
  __shared__ unsigned short As[128][40];  // +8 pad: 2-way-max bank aliasing
  __shared__ unsigned short Bs[128][40];  // Bs[n][k]

  const int z = blockIdx.z;
  A += (size_t)z * sA; Bm += (size_t)z * sB; C += (size_t)z * sC;
  const int m0 = blockIdx.y * 128;
  const int n0 = blockIdx.x * 128;
  const int t = threadIdx.x;
  const int lane = t & 63;
  const int wave = t >> 6;
  const int wm = (wave >> 1) * 64;
  const int wn = (wave & 1) * 64;
  const int fr = lane & 15;          // row (A) / col (B) within 16x16 frag
  const int kg = (lane >> 4) * 8;    // k-group of 8

  f32x4 acc[4][4] = {};

  for (int k0 = 0; k0 < K; k0 += 32) {
    {  // stage A tile [128 x 32], K contiguous
      const int r = t >> 3, cg = (t & 7) << 2;
#pragma unroll
      for (int p = 0; p < 4; ++p) {
        const int row = r + p * 32;
        const float4 v = *(const float4*)(A + (size_t)(m0 + row) * lda + (k0 + cg));
        ushort4 w;
        w.x = f2bf(v.x); w.y = f2bf(v.y); w.z = f2bf(v.z); w.w = f2bf(v.w);
        *(ushort4*)&As[row][cg] = w;
      }
    }
    if (TRANSB) {  // B stored [N,K]: same pattern as A
      const int r = t >> 3, cg = (t & 7) << 2;
#pragma unroll
      for (int p = 0; p < 4; ++p) {
        const int row = r + p * 32;
        const float4 v = *(const float4*)(Bm + (size_t)(n0 + row) * ldb + (k0 + cg));
        ushort4 w;
        w.x = f2bf(v.x); w.y = f2bf(v.y); w.z = f2bf(v.z); w.w = f2bf(v.w);
        *(ushort4*)&Bs[row][cg] = w;
      }
    } else {  // B stored [K,N]: transpose into Bs[n][k]
      const int r = t >> 5, cg = (t & 31) << 2;
#pragma unroll
      for (int p = 0; p < 4; ++p) {
        const int kk = r + p * 8;
        const float4 v = *(const float4*)(Bm + (size_t)(k0 + kk) * ldb + (n0 + cg));
        Bs[cg + 0][kk] = f2bf(v.x);
        Bs[cg + 1][kk] = f2bf(v.y);
        Bs[cg + 2][kk] = f2bf(v.z);
        Bs[cg + 3][kk] = f2bf(v.w);
      }
    }
    __syncthreads();

    bf16x8 af[4], bfr[4];
#pragma unroll
    for (int i = 0; i < 4; ++i) {
      af[i]  = __builtin_bit_cast(bf16x8, *(const u16x8*)&As[wm + i * 16 + fr][kg]);
      bfr[i] = __builtin_bit_cast(bf16x8, *(const u16x8*)&Bs[wn + i * 16 + fr][kg]);
    }
#pragma unroll
    for (int mi = 0; mi < 4; ++mi)
#pragma unroll
      for (int ni = 0; ni < 4; ++ni)
        acc[mi][ni] = __builtin_amdgcn_mfma_f32_16x16x32_bf16(
            af[mi], bfr[ni], acc[mi][ni], 0, 0, 0);
    __syncthreads();
  }

  float logd = 0.f;
  if (EPI == EPI_DECAY) logd = __logf(decayp[0]);
  const int rb = (lane >> 4) * 4;  // C/D: col=lane&15, row=(lane>>4)*4+reg
#pragma unroll
  for (int mi = 0; mi < 4; ++mi) {
#pragma unroll
    for (int ni = 0; ni < 4; ++ni) {
#pragma unroll
      for (int r = 0; r < 4; ++r) {
        const int gm = m0 + wm + mi * 16 + rb + r;
        const int gn = n0 + wn + ni * 16 + fr;
        float v = acc[mi][ni][r];
        const size_t idx = (size_t)gm * ldc + gn;
        if (EPI == EPI_BIAS) {
          C[idx] = v + bias[gn];
        } else if (EPI == EPI_GATE) {
          C[idx] = C[idx] * silu(v + bias[gn]);  // combined = conv_out*silu(gate)
        } else if (EPI == EPI_DECAY) {
          C[idx] = (gn <= gm) ? v * __expf((float)(gm - gn) * logd) : 0.f;
        } else if (EPI == EPI_RESID) {
          C[idx] = v + aux[idx];
        } else {
          C[idx] = v;
        }
      }
    }
  }
}

__global__ __launch_bounds__(256) void rmsnorm_k(const float* __restrict__ x,
                                                 const float* __restrict__ w,
                                                 float* __restrict__ o) {
  const int row = blockIdx.x;
  const float* xr = x + (size_t)row * Dd;
  float* orow = o + (size_t)row * Dd;
  const int t = threadIdx.x;
  const float4 v = *(const float4*)(xr + t * 4);
  float ss = v.x * v.x + v.y * v.y + v.z * v.z + v.w * v.w;
#pragma unroll
  for (int m = 32; m; m >>= 1) ss += __shfl_xor(ss, m);
  __shared__ float red[4];
  if ((t & 63) == 0) red[t >> 6] = ss;
  __syncthreads();
  const float total = red[0] + red[1] + red[2] + red[3];
  const float rs = rsqrtf(total * (1.f / (float)Dd) + 1e-6f);
  const float4 wt = *(const float4*)(w + t * 4);
  float4 r;
  r.x = v.x * rs * wt.x; r.y = v.y * rs * wt.y;
  r.z = v.z * rs * wt.z; r.w = v.w * rs * wt.w;
  *(float4*)(orow + t * 4) = r;
}

// causal depthwise conv (K=4, left pad 3) + bias + SiLU
__global__ __launch_bounds__(256) void conv_silu_k(const float* __restrict__ h,
                                                   const float* __restrict__ cw,
                                                   const float* __restrict__ cb,
                                                   float* __restrict__ o) {
  const long idx = (long)blockIdx.x * 256 + threadIdx.x;  // b*L*DI + t*DI + c
  const int c = (int)(idx & (DIc - 1));
  const int tpos = (int)((idx / DIc) & (Ll - 1));
  float acc = cb[c];
  const float4 w = *(const float4*)(cw + c * 4);
  const float wj[4] = {w.x, w.y, w.z, w.w};
#pragma unroll
  for (int j = 0; j < 4; ++j) {
    const int tt = tpos - 3 + j;
    if (tt >= 0) acc += wj[j] * h[idx + (long)(j - 3) * DIc];
  }
  o[idx] = silu(acc);
}

extern "C" void kernel_launch(void* const* d_in, const int* in_sizes, int n_in,
                              void* d_out, int out_size, void* d_ws,
                              size_t ws_size, hipStream_t stream) {
  const float* x      = (const float*)d_in[0];
  const float* norm_w = (const float*)d_in[1];
  const float* up_w   = (const float*)d_in[2];
  const float* up_b   = (const float*)d_in[3];
  const float* gate_w = (const float*)d_in[4];
  const float* gate_b = (const float*)d_in[5];
  const float* down_w = (const float*)d_in[6];
  const float* down_b = (const float*)d_in[7];
  const float* conv_w = (const float*)d_in[8];
  const float* conv_b = (const float*)d_in[9];
  const float* wq     = (const float*)d_in[10];
  const float* wk     = (const float*)d_in[11];
  const float* wv     = (const float*)d_in[12];
  const float* wo     = (const float*)d_in[13];
  const float* decay  = (const float*)d_in[14];
  float* out = (float*)d_out;
  float* ws  = (float*)d_ws;

  float* nrm  = ws;            // BLD: normed, later down-proj output
  float* buf1 = nrm + BLD;     // BLDI: up, later q | k
  float* buf2 = buf1 + BLDI;   // BLDI: conv/combined, later v | y
  float* S    = buf2 + BLDI;   // B*L*L

  const int MBL = Bb * Ll;  // 8192 flat rows

  rmsnorm_k<<<MBL, 256, 0, stream>>>(x, norm_w, nrm);

  // up = normed @ up_w + up_b
  gemm_k<EPI_BIAS, false><<<dim3(DIc / 128, MBL / 128, 1), 256, 0, stream>>>(
      nrm, up_w, buf1, up_b, nullptr, nullptr, MBL, DIc, Dd, Dd, DIc, DIc, 0, 0, 0);

  // buf2 = silu(conv(up) + conv_b)
  conv_silu_k<<<(unsigned)(BLDI / 256), 256, 0, stream>>>(buf1, conv_w, conv_b, buf2);

  // buf2 *= silu(normed @ gate_w + gate_b)
  gemm_k<EPI_GATE, false><<<dim3(DIc / 128, MBL / 128, 1), 256, 0, stream>>>(
      nrm, gate_w, buf2, gate_b, nullptr, nullptr, MBL, DIc, Dd, Dd, DIc, DIc, 0, 0, 0);

  // out_proj = buf2 @ down_w + down_b  (into nrm, lifetime-disjoint)
  gemm_k<EPI_BIAS, false><<<dim3(Dd / 128, MBL / 128, 1), 256, 0, stream>>>(
      buf2, down_w, nrm, down_b, nullptr, nullptr, MBL, Dd, DIc, DIc, Dd, Dd, 0, 0, 0);

  float* q = buf1;
  float* k = buf1 + BLD;
  float* v = buf2;
  float* y = buf2 + BLD;

  gemm_k<EPI_NONE, false><<<dim3(Dd / 128, MBL / 128, 1), 256, 0, stream>>>(
      nrm, wq, q, nullptr, nullptr, nullptr, MBL, Dd, Dd, Dd, Dd, Dd, 0, 0, 0);
  gemm_k<EPI_NONE, false><<<dim3(Dd / 128, MBL / 128, 1), 256, 0, stream>>>(
      nrm, wk, k, nullptr, nullptr, nullptr, MBL, Dd, Dd, Dd, Dd, Dd, 0, 0, 0);
  gemm_k<EPI_NONE, false><<<dim3(Dd / 128, MBL / 128, 1), 256, 0, stream>>>(
      nrm, wv, v, nullptr, nullptr, nullptr, MBL, Dd, Dd, Dd, Dd, Dd, 0, 0, 0);

  // S[b,t,s] = (q_t . k_s) * d^(t-s) for s<=t else 0   (B=K^T -> TRANSB)
  gemm_k<EPI_DECAY, true><<<dim3(Ll / 128, Ll / 128, Bb), 256, 0, stream>>>(
      q, k, S, nullptr, nullptr, decay, Ll, Ll, Dd, Dd, Dd, Ll,
      (long)Ll * Dd, (long)Ll * Dd, (long)Ll * Ll);

  // y = S @ v   (per batch)
  gemm_k<EPI_NONE, false><<<dim3(Dd / 128, Ll / 128, Bb), 256, 0, stream>>>(
      S, v, y, nullptr, nullptr, nullptr, Ll, Dd, Ll, Ll, Dd, Dd,
      (long)Ll * Ll, (long)Ll * Dd, (long)Ll * Dd);

  // out = x + y @ wo
  gemm_k<EPI_RESID, false><<<dim3(Dd / 128, MBL / 128, 1), 256, 0, stream>>>(
      y, wo, out, nullptr, x, nullptr, MBL, Dd, Dd, Dd, Dd, Dd, 0, 0, 0);
}

// Round 2
// 576.389 us; speedup vs baseline: 2.0332x; 2.0332x over previous
//
#include <hip/hip_runtime.h>

// Fused block, all-bf16 dataflow with m97-structure GEMMs:
// weights pre-transposed+converted to bf16 [N][K]; activations bf16;
// GEMM = 128x128 tile, BK=32, 4 waves (2x2) of 64x64, mfma_f32_16x16x32_bf16,
// global_load_lds dwordx4 staging (no VALU repack), 2-barrier K-loop.
// Decay-memory scan rewritten as causal masked attention (QK^T * d^(t-s)) @ V.

typedef __bf16 bf16x8 __attribute__((ext_vector_type(8)));
typedef unsigned short u16x8 __attribute__((ext_vector_type(8)));
typedef float f32x4 __attribute__((ext_vector_type(4)));

constexpr int Bb = 4, Ll = 2048, Dd = 1024, DIc = 2048;
constexpr long LD  = (long)Ll * Dd;       // 2,097,152
constexpr long BLD = (long)Bb * LD;       // 8,388,608
constexpr long BLDI = (long)Bb * Ll * DIc;

static __device__ __forceinline__ unsigned short f2bf(float f) {
  unsigned u = __builtin_bit_cast(unsigned, f);
  u += 0x7fffu + ((u >> 16) & 1u);  // RNE
  return (unsigned short)(u >> 16);
}
static __device__ __forceinline__ float bf2f(unsigned short u) {
  return __builtin_bit_cast(float, (unsigned)u << 16);
}
static __device__ __forceinline__ float silu(float g) {
  return g / (1.f + __expf(-g));
}

enum { EP_UP = 0, EP_GATE, EP_DOWN, EP_QKV, EP_DECAY, EP_Y, EP_WO };

// C = A[M,K] @ B[N,K]^T. A,B bf16. 128x128 tile, BK=32.
template <int EPI>
__global__ __launch_bounds__(256) void gemm_k(
    const ushort* __restrict__ A, const ushort* __restrict__ Bm,
    void* __restrict__ O0, const float* __restrict__ bias,
    const float* __restrict__ xres, const float* __restrict__ decayp,
    int N, int K, int lda, int ldb, int ldc,
    long sA, long sB, long sC,
    void* __restrict__ O1, void* __restrict__ O2) {
  __shared__ ushort lds[8192];  // As [128][32] | Bs [128][32]
  ushort* As = lds;
  ushort* Bs = lds + 4096;

  const int z = blockIdx.z;
  const int m0 = blockIdx.y * 128;
  const int n0 = blockIdx.x * 128;
  const int t = threadIdx.x;
  const int lane = t & 63;
  const int wave = t >> 6;

  if constexpr (EPI == EP_DECAY) {
    if (n0 > m0) {  // fully above diagonal: all zero
      ushort* S = (ushort*)O0 + (size_t)z * sC;
      u16x8 zz = {};
#pragma unroll
      for (int i = 0; i < 8; ++i) {
        const int row = (t >> 4) + i * 16, col = (t & 15) * 8;
        *(u16x8*)&S[(size_t)(m0 + row) * ldc + n0 + col] = zz;
      }
      return;
    }
  }

  const ushort* Ab = A + (size_t)z * sA + (size_t)m0 * lda;
  const ushort* Bb = Bm + (size_t)z * sB + (size_t)n0 * ldb;

  int Kend = K;
  if constexpr (EPI == EP_Y) Kend = (K < m0 + 128) ? K : m0 + 128;

  const int wm = (wave >> 1) * 64;
  const int wn = (wave & 1) * 64;
  const int fr = lane & 15;
  const int kg = (lane >> 4) * 8;
  const int srow0 = wave * 16 + (lane >> 2);  // staging row (p=0)
  const int scol = (lane & 3) * 8;            // staging col

  f32x4 acc[4][4] = {};

  for (int k0 = 0; k0 < Kend; k0 += 32) {
#pragma unroll
    for (int p = 0; p < 2; ++p) {
      const ushort* g = Ab + (size_t)(srow0 + p * 64) * lda + k0 + scol;
      __builtin_amdgcn_global_load_lds(
          (const __attribute__((address_space(1))) void*)g,
          (__attribute__((address_space(3))) void*)(As + (p * 4 + wave) * 512),
          16, 0, 0);
    }
#pragma unroll
    for (int p = 0; p < 2; ++p) {
      const ushort* g = Bb + (size_t)(srow0 + p * 64) * ldb + k0 + scol;
      __builtin_amdgcn_global_load_lds(
          (const __attribute__((address_space(1))) void*)g,
          (__attribute__((address_space(3))) void*)(Bs + (p * 4 + wave) * 512),
          16, 0, 0);
    }
    __syncthreads();  // drains vmcnt, publishes LDS

    bf16x8 af[4], bfv[4];
#pragma unroll
    for (int i = 0; i < 4; ++i) {
      af[i]  = __builtin_bit_cast(bf16x8, *(const u16x8*)&As[(wm + i * 16 + fr) * 32 + kg]);
      bfv[i] = __builtin_bit_cast(bf16x8, *(const u16x8*)&Bs[(wn + i * 16 + fr) * 32 + kg]);
    }
#pragma unroll
    for (int mi = 0; mi < 4; ++mi)
#pragma unroll
      for (int ni = 0; ni < 4; ++ni)
        acc[mi][ni] = __builtin_amdgcn_mfma_f32_16x16x32_bf16(
            af[mi], bfv[ni], acc[mi][ni], 0, 0, 0);
    __syncthreads();  // protect LDS before next stage
  }

  // ---- epilogue ---- C/D: col=lane&15, row=(lane>>4)*4+reg
  const int rb = (lane >> 4) * 4;
  float logd = 0.f;
  if constexpr (EPI == EP_DECAY) logd = __logf(decayp[0]);

#pragma unroll
  for (int mi = 0; mi < 4; ++mi) {
#pragma unroll
    for (int ni = 0; ni < 4; ++ni) {
      const int gm0 = m0 + wm + mi * 16 + rb;
      const int gn = n0 + wn + ni * 16 + fr;
      if constexpr (EPI == EP_QKV) {
        if (gn < 2048) {
          ushort* dst = (gn < 1024) ? (ushort*)O0 : (ushort*)O1;
          const int col = gn & 1023;
#pragma unroll
          for (int r = 0; r < 4; ++r)
            dst[(size_t)(gm0 + r) * 1024 + col] = f2bf(acc[mi][ni][r]);
        } else {  // v transposed: vT[b][d][t]
          const int d = gn - 2048, b = gm0 >> 11, tt = gm0 & 2047;
          ushort4 w4;
          w4.x = f2bf(acc[mi][ni][0]); w4.y = f2bf(acc[mi][ni][1]);
          w4.z = f2bf(acc[mi][ni][2]); w4.w = f2bf(acc[mi][ni][3]);
          *(ushort4*)&((ushort*)O2)[(size_t)b * LD + (size_t)d * Ll + tt] = w4;
        }
      } else {
#pragma unroll
        for (int r = 0; r < 4; ++r) {
          const int gm = gm0 + r;
          const size_t idx = (size_t)z * sC + (size_t)gm * ldc + gn;
          const float v = acc[mi][ni][r];
          if constexpr (EPI == EP_UP || EPI == EP_DOWN) {
            ((ushort*)O0)[idx] = f2bf(v + bias[gn]);
          } else if constexpr (EPI == EP_GATE) {
            ushort* o = (ushort*)O0;
            o[idx] = f2bf(bf2f(o[idx]) * silu(v + bias[gn]));
          } else if constexpr (EPI == EP_DECAY) {
            ((ushort*)O0)[idx] =
                (gn <= gm) ? f2bf(v * __expf((float)(gm - gn) * logd)) : (ushort)0;
          } else if constexpr (EPI == EP_Y) {
            ((ushort*)O0)[idx] = f2bf(v);
          } else {  // EP_WO
            ((float*)O0)[idx] = v + xres[idx];
          }
        }
      }
    }
  }
}

// fp32 [R][C] -> bf16 [C][R]
__global__ __launch_bounds__(256) void transpose_bf16_k(
    const float* __restrict__ src, ushort* __restrict__ dst, int R, int C) {
  __shared__ float tile[32][33];
  const int c0 = blockIdx.x * 32, r0 = blockIdx.y * 32;
  const int tx = threadIdx.x, ty = threadIdx.y;
#pragma unroll
  for (int i = 0; i < 4; ++i)
    tile[ty + i * 8][tx] = src[(size_t)(r0 + ty + i * 8) * C + c0 + tx];
  __syncthreads();
#pragma unroll
  for (int i = 0; i < 4; ++i)
    dst[(size_t)(c0 + ty + i * 8) * R + r0 + tx] = f2bf(tile[tx][ty + i * 8]);
}

__global__ __launch_bounds__(256) void rmsnorm_k(const float* __restrict__ x,
                                                 const float* __restrict__ w,
                                                 ushort* __restrict__ o) {
  const int row = blockIdx.x;
  const float* xr = x + (size_t)row * Dd;
  const int t = threadIdx.x;
  const float4 v = *(const float4*)(xr + t * 4);
  float ss = v.x * v.x + v.y * v.y + v.z * v.z + v.w * v.w;
#pragma unroll
  for (int m = 32; m; m >>= 1) ss += __shfl_xor(ss, m);
  __shared__ float red[4];
  if ((t & 63) == 0) red[t >> 6] = ss;
  __syncthreads();
  const float total = red[0] + red[1] + red[2] + red[3];
  const float rs = rsqrtf(total * (1.f / (float)Dd) + 1e-6f);
  const float4 wt = *(const float4*)(w + t * 4);
  ushort4 r;
  r.x = f2bf(v.x * rs * wt.x); r.y = f2bf(v.y * rs * wt.y);
  r.z = f2bf(v.z * rs * wt.z); r.w = f2bf(v.w * rs * wt.w);
  *(ushort4*)(o + (size_t)row * Dd + t * 4) = r;
}

// causal depthwise conv (K=4) + bias + SiLU, bf16 in/out, 8 channels/thread
__global__ __launch_bounds__(256) void conv_silu_k(const ushort* __restrict__ h,
                                                   const float* __restrict__ cw,
                                                   const float* __restrict__ cb,
                                                   ushort* __restrict__ o) {
  const int id = blockIdx.x * 256 + threadIdx.x;  // 0 .. BLDI/8
  const int cg = id & 255;          // channel group (DI/8 = 256)
  const int row = id >> 8;          // flat b*L + t
  const int tpos = row & (Ll - 1);
  const int c = cg * 8;
  float acc[8];
#pragma unroll
  for (int j = 0; j < 8; ++j) acc[j] = cb[c + j];
#pragma unroll
  for (int k = 0; k < 4; ++k) {
    const int tt = tpos - 3 + k;
    if (tt < 0) continue;
    const u16x8 hv = *(const u16x8*)&h[(size_t)(row + k - 3) * DIc + c];
#pragma unroll
    for (int j = 0; j < 8; ++j) acc[j] += bf2f(hv[j]) * cw[(c + j) * 4 + k];
  }
  u16x8 ov;
#pragma unroll
  for (int j = 0; j < 8; ++j) ov[j] = f2bf(silu(acc[j]));
  *(u16x8*)&o[(size_t)row * DIc + c] = ov;
}

extern "C" void kernel_launch(void* const* d_in, const int* in_sizes, int n_in,
                              void* d_out, int out_size, void* d_ws,
                              size_t ws_size, hipStream_t stream) {
  const float* x      = (const float*)d_in[0];
  const float* norm_w = (const float*)d_in[1];
  const float* up_w   = (const float*)d_in[2];
  const float* up_b   = (const float*)d_in[3];
  const float* gate_w = (const float*)d_in[4];
  const float* gate_b = (const float*)d_in[5];
  const float* down_w = (const float*)d_in[6];
  const float* down_b = (const float*)d_in[7];
  const float* conv_w = (const float*)d_in[8];
  const float* conv_b = (const float*)d_in[9];
  const float* wq     = (const float*)d_in[10];
  const float* wk     = (const float*)d_in[11];
  const float* wv     = (const float*)d_in[12];
  const float* wo     = (const float*)d_in[13];
  const float* decay  = (const float*)d_in[14];
  float* out = (float*)d_out;
  char* w8 = (char*)d_ws;

  const size_t MiB = 1u << 20;
  ushort* nrm     = (ushort*)(w8 + 0 * MiB);    // 16 MiB: normed, later down-out
  ushort* buf1    = (ushort*)(w8 + 16 * MiB);   // 32 MiB: up, later q|k
  ushort* buf2    = (ushort*)(w8 + 48 * MiB);   // 32 MiB: conv/combined, later vT|y
  ushort* S       = (ushort*)(w8 + 80 * MiB);   // 32 MiB
  ushort* up_wT   = (ushort*)(w8 + 112 * MiB);  // 4 MiB [2048][1024]
  ushort* gate_wT = (ushort*)(w8 + 116 * MiB);  // 4 MiB
  ushort* down_wT = (ushort*)(w8 + 120 * MiB);  // 4 MiB [1024][2048]
  ushort* qkv_wT  = (ushort*)(w8 + 124 * MiB);  // 6 MiB [3072][1024]
  ushort* wo_T    = (ushort*)(w8 + 130 * MiB);  // 2 MiB

  ushort* q  = buf1;
  ushort* kb = buf1 + BLD;
  ushort* vT = buf2;
  ushort* y  = buf2 + BLD;

  const dim3 tb(32, 8);
  transpose_bf16_k<<<dim3(64, 32), tb, 0, stream>>>(up_w, up_wT, 1024, 2048);
  transpose_bf16_k<<<dim3(64, 32), tb, 0, stream>>>(gate_w, gate_wT, 1024, 2048);
  transpose_bf16_k<<<dim3(32, 64), tb, 0, stream>>>(down_w, down_wT, 2048, 1024);
  transpose_bf16_k<<<dim3(32, 32), tb, 0, stream>>>(wq, qkv_wT, 1024, 1024);
  transpose_bf16_k<<<dim3(32, 32), tb, 0, stream>>>(wk, qkv_wT + 1024 * 1024, 1024, 1024);
  transpose_bf16_k<<<dim3(32, 32), tb, 0, stream>>>(wv, qkv_wT + 2 * 1024 * 1024, 1024, 1024);
  transpose_bf16_k<<<dim3(32, 32), tb, 0, stream>>>(wo, wo_T, 1024, 1024);

  rmsnorm_k<<<Bb * Ll, 256, 0, stream>>>(x, norm_w, nrm);

  // up = normed @ up_w + b
  gemm_k<EP_UP><<<dim3(16, 64), 256, 0, stream>>>(
      nrm, up_wT, buf1, up_b, nullptr, nullptr,
      2048, 1024, 1024, 1024, 2048, 0, 0, 0, nullptr, nullptr);

  conv_silu_k<<<(unsigned)(BLDI / (256 * 8)) * 256 / 256 * 1, 256, 0, stream>>>(
      buf1, conv_w, conv_b, buf2);

  // combined = conv_out * silu(normed @ gate_w + b)
  gemm_k<EP_GATE><<<dim3(16, 64), 256, 0, stream>>>(
      nrm, gate_wT, buf2, gate_b, nullptr, nullptr,
      2048, 1024, 1024, 1024, 2048, 0, 0, 0, nullptr, nullptr);

  // down-out = combined @ down_w + b   (into nrm, lifetime-disjoint)
  gemm_k<EP_DOWN><<<dim3(8, 64), 256, 0, stream>>>(
      buf2, down_wT, nrm, down_b, nullptr, nullptr,
      1024, 2048, 2048, 2048, 1024, 0, 0, 0, nullptr, nullptr);

  // q|k|vT = down-out @ [wq|wk|wv]
  gemm_k<EP_QKV><<<dim3(24, 64), 256, 0, stream>>>(
      nrm, qkv_wT, q, nullptr, nullptr, nullptr,
      3072, 1024, 1024, 1024, 0, 0, 0, 0, kb, vT);

  // S = tril(q k^T) * d^(t-s)
  gemm_k<EP_DECAY><<<dim3(16, 16, Bb), 256, 0, stream>>>(
      q, kb, S, nullptr, nullptr, decay,
      2048, 1024, 1024, 1024, 2048, LD, LD, (long)Ll * Ll, nullptr, nullptr);

  // y = S @ v  (K clamped to m0+128 by causality)
  gemm_k<EP_Y><<<dim3(8, 16, Bb), 256, 0, stream>>>(
      S, vT, y, nullptr, nullptr, nullptr,
      1024, 2048, 2048, 2048, 1024, (long)Ll * Ll, LD, LD, nullptr, nullptr);

  // out = x + y @ wo
  gemm_k<EP_WO><<<dim3(8, 64), 256, 0, stream>>>(
      y, wo_T, out, nullptr, x, nullptr,
      1024, 1024, 1024, 1024, 1024, 0, 0, 0, nullptr, nullptr);
}

// Round 3
// 436.590 us; speedup vs baseline: 2.6842x; 1.3202x over previous
//
#include <hip/hip_runtime.h>

// Fused block, all-bf16 dataflow, m97-structure GEMMs + XCD swizzle:
// - up|gate fused into one N=4096 GEMM
// - conv+SiLU+gating fused into one sliding-window kernel (prepacked weights)
// - decay scan as causal masked attention (QK^T * d^(t-s)) @ V

typedef __bf16 bf16x8 __attribute__((ext_vector_type(8)));
typedef unsigned short u16x8 __attribute__((ext_vector_type(8)));
typedef float f32x4 __attribute__((ext_vector_type(4)));

constexpr int Bb = 4, Ll = 2048, Dd = 1024, DIc = 2048;
constexpr long LD  = (long)Ll * Dd;   // 2,097,152
constexpr long BLD = (long)Bb * LD;   // 8,388,608

static __device__ __forceinline__ unsigned short f2bf(float f) {
  unsigned u = __builtin_bit_cast(unsigned, f);
  u += 0x7fffu + ((u >> 16) & 1u);  // RNE
  return (unsigned short)(u >> 16);
}
static __device__ __forceinline__ float bf2f(unsigned short u) {
  return __builtin_bit_cast(float, (unsigned)u << 16);
}
static __device__ __forceinline__ float silu(float g) {
  return g / (1.f + __expf(-g));
}

enum { EP_UG = 0, EP_DOWN, EP_QKV, EP_DECAY, EP_Y, EP_WO };

// C = A[M,K] @ B[N,K]^T. A,B bf16. 128x128 tile, BK=32, global_load_lds staging.
// bias2: second bias (gate_b) for EP_UG; xres: fp32 residual for EP_WO.
template <int EPI>
__global__ __launch_bounds__(256) void gemm_k(
    const ushort* __restrict__ A, const ushort* __restrict__ Bm,
    void* __restrict__ O0, const float* __restrict__ bias,
    const float* __restrict__ bias2, const float* __restrict__ xres,
    const float* __restrict__ decayp,
    int N, int K, int lda, int ldb, int ldc,
    long sA, long sB, long sC,
    void* __restrict__ O1, void* __restrict__ O2) {
  __shared__ ushort lds[8192];  // As [128][32] | Bs [128][32]
  ushort* As = lds;
  ushort* Bs = lds + 4096;

  const int z = blockIdx.z;
  // XCD-aware bijective swizzle (per-z grid size always % 8 == 0 here)
  const int gx = gridDim.x;
  const int nwg = gx * gridDim.y;
  const int id = blockIdx.y * gx + blockIdx.x;
  const int chunk = nwg >> 3;
  const int swz = (id & 7) * chunk + (id >> 3);
  const int m0 = (swz / gx) * 128;
  const int n0 = (swz % gx) * 128;

  const int t = threadIdx.x;
  const int lane = t & 63;
  const int wave = t >> 6;

  if constexpr (EPI == EP_DECAY) {
    if (n0 > m0) {  // fully above diagonal: all zero
      ushort* S = (ushort*)O0 + (size_t)z * sC;
      u16x8 zz = {};
#pragma unroll
      for (int i = 0; i < 8; ++i) {
        const int row = (t >> 4) + i * 16, col = (t & 15) * 8;
        *(u16x8*)&S[(size_t)(m0 + row) * ldc + n0 + col] = zz;
      }
      return;
    }
  }

  const ushort* Ab = A + (size_t)z * sA + (size_t)m0 * lda;
  const ushort* Bbp = Bm + (size_t)z * sB + (size_t)n0 * ldb;

  int Kend = K;
  if constexpr (EPI == EP_Y) Kend = (K < m0 + 128) ? K : m0 + 128;

  const int wm = (wave >> 1) * 64;
  const int wn = (wave & 1) * 64;
  const int fr = lane & 15;
  const int kg = (lane >> 4) * 8;
  const int srow0 = wave * 16 + (lane >> 2);  // staging row (p=0)
  const int scol = (lane & 3) * 8;            // staging col

  f32x4 acc[4][4] = {};

  for (int k0 = 0; k0 < Kend; k0 += 32) {
#pragma unroll
    for (int p = 0; p < 2; ++p) {
      const ushort* g = Ab + (size_t)(srow0 + p * 64) * lda + k0 + scol;
      __builtin_amdgcn_global_load_lds(
          (const __attribute__((address_space(1))) void*)g,
          (__attribute__((address_space(3))) void*)(As + (p * 4 + wave) * 512),
          16, 0, 0);
    }
#pragma unroll
    for (int p = 0; p < 2; ++p) {
      const ushort* g = Bbp + (size_t)(srow0 + p * 64) * ldb + k0 + scol;
      __builtin_amdgcn_global_load_lds(
          (const __attribute__((address_space(1))) void*)g,
          (__attribute__((address_space(3))) void*)(Bs + (p * 4 + wave) * 512),
          16, 0, 0);
    }
    __syncthreads();

    bf16x8 af[4], bfv[4];
#pragma unroll
    for (int i = 0; i < 4; ++i) {
      af[i]  = __builtin_bit_cast(bf16x8, *(const u16x8*)&As[(wm + i * 16 + fr) * 32 + kg]);
      bfv[i] = __builtin_bit_cast(bf16x8, *(const u16x8*)&Bs[(wn + i * 16 + fr) * 32 + kg]);
    }
#pragma unroll
    for (int mi = 0; mi < 4; ++mi)
#pragma unroll
      for (int ni = 0; ni < 4; ++ni)
        acc[mi][ni] = __builtin_amdgcn_mfma_f32_16x16x32_bf16(
            af[mi], bfv[ni], acc[mi][ni], 0, 0, 0);
    __syncthreads();
  }

  // ---- epilogue ---- C/D: col=lane&15, row=(lane>>4)*4+reg
  const int rb = (lane >> 4) * 4;
  float logd = 0.f;
  if constexpr (EPI == EP_DECAY) logd = __logf(decayp[0]);

#pragma unroll
  for (int mi = 0; mi < 4; ++mi) {
#pragma unroll
    for (int ni = 0; ni < 4; ++ni) {
      const int gm0 = m0 + wm + mi * 16 + rb;
      const int gn = n0 + wn + ni * 16 + fr;
      if constexpr (EPI == EP_QKV) {
        if (gn < 2048) {
          ushort* dst = (gn < 1024) ? (ushort*)O0 : (ushort*)O1;
          const int col = gn & 1023;
#pragma unroll
          for (int r = 0; r < 4; ++r)
            dst[(size_t)(gm0 + r) * 1024 + col] = f2bf(acc[mi][ni][r]);
        } else {  // v transposed: vT[b][d][t]
          const int d = gn - 2048, b = gm0 >> 11, tt = gm0 & 2047;
          ushort4 w4;
          w4.x = f2bf(acc[mi][ni][0]); w4.y = f2bf(acc[mi][ni][1]);
          w4.z = f2bf(acc[mi][ni][2]); w4.w = f2bf(acc[mi][ni][3]);
          *(ushort4*)&((ushort*)O2)[(size_t)b * LD + (size_t)d * Ll + tt] = w4;
        }
      } else {
#pragma unroll
        for (int r = 0; r < 4; ++r) {
          const int gm = gm0 + r;
          const size_t idx = (size_t)z * sC + (size_t)gm * ldc + gn;
          const float v = acc[mi][ni][r];
          if constexpr (EPI == EP_UG) {
            const float b = (gn < 2048) ? bias[gn] : bias2[gn - 2048];
            ((ushort*)O0)[idx] = f2bf(v + b);
          } else if constexpr (EPI == EP_DOWN) {
            ((ushort*)O0)[idx] = f2bf(v + bias[gn]);
          } else if constexpr (EPI == EP_DECAY) {
            ((ushort*)O0)[idx] =
                (gn <= gm) ? f2bf(v * __expf((float)(gm - gn) * logd)) : (ushort)0;
          } else if constexpr (EPI == EP_Y) {
            ((ushort*)O0)[idx] = f2bf(v);
          } else {  // EP_WO
            ((float*)O0)[idx] = v + xres[idx];
          }
        }
      }
    }
  }
}

// fp32 [R][C] -> bf16 [C][R]
__global__ __launch_bounds__(256) void transpose_bf16_k(
    const float* __restrict__ src, ushort* __restrict__ dst, int R, int C) {
  __shared__ float tile[32][33];
  const int c0 = blockIdx.x * 32, r0 = blockIdx.y * 32;
  const int tx = threadIdx.x, ty = threadIdx.y;
#pragma unroll
  for (int i = 0; i < 4; ++i)
    tile[ty + i * 8][tx] = src[(size_t)(r0 + ty + i * 8) * C + c0 + tx];
  __syncthreads();
#pragma unroll
  for (int i = 0; i < 4; ++i)
    dst[(size_t)(c0 + ty + i * 8) * R + r0 + tx] = f2bf(tile[tx][ty + i * 8]);
}

// conv_w [DI][4] fp32 -> cwT [4][DI] bf16
__global__ __launch_bounds__(256) void pack_convw_k(const float* __restrict__ cw,
                                                    ushort* __restrict__ cwT) {
  const int c = blockIdx.x * 256 + threadIdx.x;
  const float4 v = *(const float4*)(cw + c * 4);
  cwT[0 * DIc + c] = f2bf(v.x);
  cwT[1 * DIc + c] = f2bf(v.y);
  cwT[2 * DIc + c] = f2bf(v.z);
  cwT[3 * DIc + c] = f2bf(v.w);
}

__global__ __launch_bounds__(256) void rmsnorm_k(const float* __restrict__ x,
                                                 const float* __restrict__ w,
                                                 ushort* __restrict__ o) {
  const int row = blockIdx.x;
  const float* xr = x + (size_t)row * Dd;
  const int t = threadIdx.x;
  const float4 v = *(const float4*)(xr + t * 4);
  float ss = v.x * v.x + v.y * v.y + v.z * v.z + v.w * v.w;
#pragma unroll
  for (int m = 32; m; m >>= 1) ss += __shfl_xor(ss, m);
  __shared__ float red[4];
  if ((t & 63) == 0) red[t >> 6] = ss;
  __syncthreads();
  const float total = red[0] + red[1] + red[2] + red[3];
  const float rs = rsqrtf(total * (1.f / (float)Dd) + 1e-6f);
  const float4 wt = *(const float4*)(w + t * 4);
  ushort4 r;
  r.x = f2bf(v.x * rs * wt.x); r.y = f2bf(v.y * rs * wt.y);
  r.z = f2bf(v.z * rs * wt.z); r.w = f2bf(v.w * rs * wt.w);
  *(ushort4*)(o + (size_t)row * Dd + t * 4) = r;
}

// combined = silu(conv(up)+cb) * silu(gate)
// ug: [8192][4096] bf16, cols 0..2047 = up, 2048..4095 = gate.
// Sliding window: 8 channels x 8 timesteps per thread.
__global__ __launch_bounds__(256) void conv_gate_k(
    const ushort* __restrict__ ug, const ushort* __restrict__ cwT,
    const float* __restrict__ cb, ushort* __restrict__ o) {
  const int t = threadIdx.x;
  const int cg = t & 31;             // 32 channel-groups of 8
  const int ts = t >> 5;             // 8 time-strips of 8
  const int cblk = blockIdx.x & 7;   // 8 channel blocks (8*256 = 2048 ch)
  const int rblk = blockIdx.x >> 3;  // 128 row blocks of 64
  const int c = cblk * 256 + cg * 8;
  const int row0 = rblk * 64 + ts * 8;

  u16x8 w[4];
#pragma unroll
  for (int k = 0; k < 4; ++k) w[k] = *(const u16x8*)&cwT[k * DIc + c];
  float wb[8];
  *(float4*)&wb[0] = *(const float4*)(cb + c);
  *(float4*)&wb[4] = *(const float4*)(cb + c + 4);

  u16x8 h3, h2, h1;
  if ((row0 & (Ll - 1)) == 0) {
    h3 = (u16x8){}; h2 = (u16x8){}; h1 = (u16x8){};
  } else {
    h3 = *(const u16x8*)&ug[(size_t)(row0 - 3) * 4096 + c];
    h2 = *(const u16x8*)&ug[(size_t)(row0 - 2) * 4096 + c];
    h1 = *(const u16x8*)&ug[(size_t)(row0 - 1) * 4096 + c];
  }

#pragma unroll
  for (int i = 0; i < 8; ++i) {
    const size_t rbase = (size_t)(row0 + i) * 4096;
    const u16x8 h0 = *(const u16x8*)&ug[rbase + c];
    const u16x8 g  = *(const u16x8*)&ug[rbase + 2048 + c];
    u16x8 ov;
#pragma unroll
    for (int j = 0; j < 8; ++j) {
      float acc = wb[j];
      acc += bf2f(w[0][j]) * bf2f(h3[j]);
      acc += bf2f(w[1][j]) * bf2f(h2[j]);
      acc += bf2f(w[2][j]) * bf2f(h1[j]);
      acc += bf2f(w[3][j]) * bf2f(h0[j]);
      ov[j] = f2bf(silu(acc) * silu(bf2f(g[j])));
    }
    *(u16x8*)&o[(size_t)(row0 + i) * DIc + c] = ov;
    h3 = h2; h2 = h1; h1 = h0;
  }
}

extern "C" void kernel_launch(void* const* d_in, const int* in_sizes, int n_in,
                              void* d_out, int out_size, void* d_ws,
                              size_t ws_size, hipStream_t stream) {
  const float* x      = (const float*)d_in[0];
  const float* norm_w = (const float*)d_in[1];
  const float* up_w   = (const float*)d_in[2];
  const float* up_b   = (const float*)d_in[3];
  const float* gate_w = (const float*)d_in[4];
  const float* gate_b = (const float*)d_in[5];
  const float* down_w = (const float*)d_in[6];
  const float* down_b = (const float*)d_in[7];
  const float* conv_w = (const float*)d_in[8];
  const float* conv_b = (const float*)d_in[9];
  const float* wq     = (const float*)d_in[10];
  const float* wk     = (const float*)d_in[11];
  const float* wv     = (const float*)d_in[12];
  const float* wo     = (const float*)d_in[13];
  const float* decay  = (const float*)d_in[14];
  float* out = (float*)d_out;
  char* w8 = (char*)d_ws;

  const size_t MiB = 1u << 20;
  ushort* nrm      = (ushort*)(w8 + 0 * MiB);    // 16: normed, later down-out
  ushort* ug       = (ushort*)(w8 + 16 * MiB);   // 64: up|gate [8192][4096]
  ushort* S        = (ushort*)(w8 + 16 * MiB);   // 32 (aliases ug; disjoint life)
  ushort* combined = (ushort*)(w8 + 80 * MiB);   // 32
  ushort* buf1     = (ushort*)(w8 + 112 * MiB);  // 32: q|k
  ushort* buf2     = (ushort*)(w8 + 144 * MiB);  // 32: vT|y
  ushort* ugw      = (ushort*)(w8 + 176 * MiB);  // 8: [4096][1024] up_wT|gate_wT
  ushort* down_wT  = (ushort*)(w8 + 184 * MiB);  // 4: [1024][2048]
  ushort* qkv_wT   = (ushort*)(w8 + 188 * MiB);  // 6: [3072][1024]
  ushort* wo_T     = (ushort*)(w8 + 194 * MiB);  // 2
  ushort* cwT      = (ushort*)(w8 + 196 * MiB);  // 16 KiB

  ushort* q  = buf1;
  ushort* kb = buf1 + BLD;
  ushort* vT = buf2;
  ushort* y  = buf2 + BLD;

  const dim3 tb(32, 8);
  transpose_bf16_k<<<dim3(64, 32), tb, 0, stream>>>(up_w, ugw, 1024, 2048);
  transpose_bf16_k<<<dim3(64, 32), tb, 0, stream>>>(gate_w, ugw + 2048 * 1024, 1024, 2048);
  transpose_bf16_k<<<dim3(32, 64), tb, 0, stream>>>(down_w, down_wT, 2048, 1024);
  transpose_bf16_k<<<dim3(32, 32), tb, 0, stream>>>(wq, qkv_wT, 1024, 1024);
  transpose_bf16_k<<<dim3(32, 32), tb, 0, stream>>>(wk, qkv_wT + 1024 * 1024, 1024, 1024);
  transpose_bf16_k<<<dim3(32, 32), tb, 0, stream>>>(wv, qkv_wT + 2 * 1024 * 1024, 1024, 1024);
  transpose_bf16_k<<<dim3(32, 32), tb, 0, stream>>>(wo, wo_T, 1024, 1024);
  pack_convw_k<<<8, 256, 0, stream>>>(conv_w, cwT);

  rmsnorm_k<<<Bb * Ll, 256, 0, stream>>>(x, norm_w, nrm);

  // ug = normed @ [up_w|gate_w] + [up_b|gate_b]
  gemm_k<EP_UG><<<dim3(32, 64), 256, 0, stream>>>(
      nrm, ugw, ug, up_b, gate_b, nullptr, nullptr,
      4096, 1024, 1024, 1024, 4096, 0, 0, 0, nullptr, nullptr);

  // combined = silu(conv(up)+cb) * silu(gate)
  conv_gate_k<<<1024, 256, 0, stream>>>(ug, cwT, conv_b, combined);

  // down-out = combined @ down_w + b   (into nrm, lifetime-disjoint)
  gemm_k<EP_DOWN><<<dim3(8, 64), 256, 0, stream>>>(
      combined, down_wT, nrm, down_b, nullptr, nullptr, nullptr,
      1024, 2048, 2048, 2048, 1024, 0, 0, 0, nullptr, nullptr);

  // q|k|vT = down-out @ [wq|wk|wv]
  gemm_k<EP_QKV><<<dim3(24, 64), 256, 0, stream>>>(
      nrm, qkv_wT, q, nullptr, nullptr, nullptr, nullptr,
      3072, 1024, 1024, 1024, 0, 0, 0, 0, kb, vT);

  // S = tril(q k^T) * d^(t-s)
  gemm_k<EP_DECAY><<<dim3(16, 16, Bb), 256, 0, stream>>>(
      q, kb, S, nullptr, nullptr, nullptr, decay,
      2048, 1024, 1024, 1024, 2048, LD, LD, (long)Ll * Ll, nullptr, nullptr);

  // y = S @ v  (K clamped to m0+128 by causality)
  gemm_k<EP_Y><<<dim3(8, 16, Bb), 256, 0, stream>>>(
      S, vT, y, nullptr, nullptr, nullptr, nullptr,
      1024, 2048, 2048, 2048, 1024, (long)Ll * Ll, LD, LD, nullptr, nullptr);

  // out = x + y @ wo
  gemm_k<EP_WO><<<dim3(8, 64), 256, 0, stream>>>(
      y, wo_T, out, nullptr, nullptr, x, nullptr,
      1024, 1024, 1024, 1024, 1024, 0, 0, 0, nullptr, nullptr);
}

// Round 4
// 381.528 us; speedup vs baseline: 3.0716x; 1.1443x over previous
//
#include <hip/hip_runtime.h>

// Fused block, all-bf16 dataflow. GEMMs use the 256x256 8-phase template:
// BK=64, 8 waves (2Mx4N), 128 KiB double-buffered LDS, st_16x32 swizzle,
// counted vmcnt(6) at phases 4/8 only, setprio around MFMA clusters.
// Decay-memory scan computed as causal masked attention (QK^T * d^(t-s)) @ V.

typedef __bf16 bf16x8 __attribute__((ext_vector_type(8)));
typedef unsigned short u16x8 __attribute__((ext_vector_type(8)));
typedef float f32x4 __attribute__((ext_vector_type(4)));

constexpr int Bb = 4, Ll = 2048, Dd = 1024, DIc = 2048;
constexpr long LD  = (long)Ll * Dd;   // 2,097,152
constexpr long BLD = (long)Bb * LD;   // 8,388,608

static __device__ __forceinline__ unsigned short f2bf(float f) {
  unsigned u = __builtin_bit_cast(unsigned, f);
  u += 0x7fffu + ((u >> 16) & 1u);  // RNE
  return (unsigned short)(u >> 16);
}
static __device__ __forceinline__ float bf2f(unsigned short u) {
  return __builtin_bit_cast(float, (unsigned)u << 16);
}
static __device__ __forceinline__ float silu(float g) {
  return g / (1.f + __expf(-g));
}

enum { EP_UG = 0, EP_DOWN, EP_QKV, EP_DECAY, EP_Y, EP_WO };

// LDS map (ushort idx): A: dbuf*16384 + kh*8192 + rb*512 + subtile(512)
//                       B: 32768 + same. rb = 16-row x 32-col swizzled subtile.
#define STAGE_A(DBUF, MG, KH, TILE) {                                          \
    const int kt_ = ((TILE) < NTm1 ? (TILE) : NTm1);                           \
    __builtin_amdgcn_global_load_lds(                                          \
      (const __attribute__((address_space(1))) void*)                          \
        (Ag + (size_t)(aRow + (MG)*64) * lda + kt_*64 + (KH)*32 + aCol),       \
      (__attribute__((address_space(3))) void*)                                \
        (lds + (DBUF)*16384 + (KH)*8192 + (aRb + (MG)*4)*512), 16, 0, 0); }

#define STAGE_B(DBUF, NH, KH, TILE) {                                          \
    const int kt_ = ((TILE) < NTm1 ? (TILE) : NTm1);                           \
    __builtin_amdgcn_global_load_lds(                                          \
      (const __attribute__((address_space(1))) void*)                          \
        (Bg + (size_t)(bRow + (NH)*128) * ldb + kt_*64 + (KH)*32 + aCol),      \
      (__attribute__((address_space(3))) void*)                                \
        (lds + 32768 + (DBUF)*16384 + (KH)*8192 + ((NH)*8 + w)*512), 16, 0, 0); }

#define LOAD_A(DBUF, KS, MG) {                                                 \
  _Pragma("unroll") for (int j_ = 0; j_ < 4; ++j_)                             \
    af[j_] = *(const bf16x8*)&lds[(DBUF)*16384 + (KS)*8192 +                   \
        ((w>>2)*8 + (MG)*4 + j_)*512 + fr*32 + cph]; }

#define LOAD_B(DBUF, KS) {                                                     \
  _Pragma("unroll") for (int n_ = 0; n_ < 4; ++n_)                             \
    bfr[KS][n_] = *(const bf16x8*)&lds[32768 + (DBUF)*16384 + (KS)*8192 +      \
        (bRb + n_)*512 + fr*32 + cph]; }

#define MFMA_PH(KS, MG) {                                                      \
  __builtin_amdgcn_s_setprio(1);                                              \
  _Pragma("unroll") for (int j_ = 0; j_ < 4; ++j_)                             \
  _Pragma("unroll") for (int n_ = 0; n_ < 4; ++n_)                             \
    acc[(MG)*4 + j_][n_] = __builtin_amdgcn_mfma_f32_16x16x32_bf16(            \
        af[j_], bfr[KS][n_], acc[(MG)*4 + j_][n_], 0, 0, 0);                   \
  __builtin_amdgcn_s_setprio(0); }

#define BAR() __builtin_amdgcn_s_barrier()
#define WAIT_LGKM0() { asm volatile("s_waitcnt lgkmcnt(0)" ::: "memory");      \
                       __builtin_amdgcn_sched_barrier(0); }

template <int EPI>
__global__ __launch_bounds__(512, 2) void gemm8_k(
    const ushort* __restrict__ A, const ushort* __restrict__ Bm,
    void* __restrict__ O0, const float* __restrict__ bias,
    const float* __restrict__ bias2, const float* __restrict__ xres,
    const float* __restrict__ decayp,
    int K, int lda, int ldb, int ldc,
    long sA, long sB, long sC,
    void* __restrict__ O1, void* __restrict__ O2) {
  __shared__ ushort lds[65536];  // 128 KiB

  const int z = blockIdx.z;
  const int gx = gridDim.x;
  const int nwg = gx * gridDim.y;
  const int id = blockIdx.y * gx + blockIdx.x;
  const int chunk = nwg >> 3;
  const int swz = (id & 7) * chunk + (id >> 3);
  const int m0 = (swz / gx) * 256;
  const int n0 = (swz % gx) * 256;

  const int t = threadIdx.x;
  const int lane = t & 63;
  const int w = t >> 6;

  if constexpr (EPI == EP_DECAY) {
    if (n0 > m0) {  // fully above diagonal: zero-fill
      ushort* S = (ushort*)O0 + (size_t)z * sC;
      u16x8 zz = {};
#pragma unroll
      for (int i = 0; i < 16; ++i) {
        const int cid = i * 512 + t;
        *(u16x8*)&S[(size_t)(m0 + (cid >> 5)) * ldc + n0 + (cid & 31) * 8] = zz;
      }
      return;
    }
  }

  const ushort* Ag = A + (size_t)z * sA + (size_t)m0 * lda;
  const ushort* Bg = Bm + (size_t)z * sB + (size_t)n0 * ldb;

  int Kend = K;
  if constexpr (EPI == EP_Y) Kend = (K < m0 + 256) ? K : m0 + 256;
  const int NT = Kend >> 6;  // 64-deep K-tiles (always >= 4 here)
  const int NTm1 = NT - 1;
  const int NI = NT >> 1;

  // stage-side: lane' = lane ^ ((lane>>5)<<1) pre-applies the LDS swizzle
  const int lp = lane ^ (((lane >> 5) & 1) << 1);
  const int aRow = (w >> 2) * 128 + (w & 3) * 16 + (lp >> 2);
  const int aCol = (lp & 3) * 8;
  const int aRb = (w >> 2) * 8 + (w & 3);
  const int bRow = (w >> 2) * 64 + (w & 3) * 16 + (lp >> 2);
  // read-side
  const int fr = lane & 15;
  const int kg = (lane >> 4) * 8;
  const int cph = kg ^ (((fr >> 3) & 1) << 4);  // st_16x32 swizzle
  const int bRb = ((w & 3) >> 1) * 8 + ((w & 3) & 1) * 4;

  f32x4 acc[8][4] = {};
  bf16x8 af[4], bfr[2][4];

  // ---- prologue: tile0 full (8 units) + tile1 B(4) + A(mg0)(2) ----
  STAGE_A(0, 0, 0, 0); STAGE_A(0, 0, 1, 0); STAGE_A(0, 1, 0, 0); STAGE_A(0, 1, 1, 0);
  STAGE_B(0, 0, 0, 0); STAGE_B(0, 0, 1, 0); STAGE_B(0, 1, 0, 0); STAGE_B(0, 1, 1, 0);
  STAGE_B(1, 0, 0, 1); STAGE_B(1, 0, 1, 1); STAGE_B(1, 1, 0, 1); STAGE_B(1, 1, 1, 1);
  STAGE_A(1, 0, 0, 1); STAGE_A(1, 0, 1, 1);
  asm volatile("s_waitcnt vmcnt(6)" ::: "memory");
  BAR();

  for (int i = 0; i < NI; ++i) {
    const int tt = 2 * i;
    // ph1: tile t (buf0) ks0 mg0 | stage A(mg1)[t+1] -> buf1
    LOAD_B(0, 0); LOAD_B(0, 1); LOAD_A(0, 0, 0);
    STAGE_A(1, 1, 0, tt + 1); STAGE_A(1, 1, 1, tt + 1);
    asm volatile("s_waitcnt lgkmcnt(8)" ::: "memory");
    BAR(); WAIT_LGKM0();
    MFMA_PH(0, 0);
    BAR();
    // ph2: ks0 mg1 | stage B(kh0)[t+2] -> buf0
    LOAD_A(0, 0, 1);
    STAGE_B(0, 0, 0, tt + 2); STAGE_B(0, 1, 0, tt + 2);
    BAR(); WAIT_LGKM0();
    MFMA_PH(0, 1);
    BAR();
    // ph3: ks1 mg0 | stage B(kh1)[t+2]
    LOAD_A(0, 1, 0);
    STAGE_B(0, 0, 1, tt + 2); STAGE_B(0, 1, 1, tt + 2);
    BAR(); WAIT_LGKM0();
    MFMA_PH(1, 0);
    BAR();
    // ph4: ks1 mg1 | stage A(mg0)[t+2]; vmcnt(6)
    LOAD_A(0, 1, 1);
    STAGE_A(0, 0, 0, tt + 2); STAGE_A(0, 0, 1, tt + 2);
    asm volatile("s_waitcnt vmcnt(6)" ::: "memory");
    BAR(); WAIT_LGKM0();
    MFMA_PH(1, 1);
    BAR();
    // ph5: tile t+1 (buf1) ks0 mg0 | stage A(mg1)[t+2] -> buf0
    LOAD_B(1, 0); LOAD_B(1, 1); LOAD_A(1, 0, 0);
    STAGE_A(0, 1, 0, tt + 2); STAGE_A(0, 1, 1, tt + 2);
    asm volatile("s_waitcnt lgkmcnt(8)" ::: "memory");
    BAR(); WAIT_LGKM0();
    MFMA_PH(0, 0);
    BAR();
    // ph6: ks0 mg1 | stage B(kh0)[t+3] -> buf1
    LOAD_A(1, 0, 1);
    STAGE_B(1, 0, 0, tt + 3); STAGE_B(1, 1, 0, tt + 3);
    BAR(); WAIT_LGKM0();
    MFMA_PH(0, 1);
    BAR();
    // ph7: ks1 mg0 | stage B(kh1)[t+3]
    LOAD_A(1, 1, 0);
    STAGE_B(1, 0, 1, tt + 3); STAGE_B(1, 1, 1, tt + 3);
    BAR(); WAIT_LGKM0();
    MFMA_PH(1, 0);
    BAR();
    // ph8: ks1 mg1 | stage A(mg0)[t+3] -> buf1; vmcnt(6)
    LOAD_A(1, 1, 1);
    STAGE_A(1, 0, 0, tt + 3); STAGE_A(1, 0, 1, tt + 3);
    asm volatile("s_waitcnt vmcnt(6)" ::: "memory");
    BAR(); WAIT_LGKM0();
    MFMA_PH(1, 1);
    BAR();
  }

  // ---- epilogue ---- C/D: col=lane&15, row=(lane>>4)*4+reg
  const int rb4 = (lane >> 4) * 4;
  const int wm = (w >> 2) * 128, wn = (w & 3) * 64;
  float logd = 0.f;
  if constexpr (EPI == EP_DECAY) logd = __logf(decayp[0]);

#pragma unroll
  for (int mf = 0; mf < 8; ++mf) {
#pragma unroll
    for (int nf = 0; nf < 4; ++nf) {
      const int gm0 = m0 + wm + mf * 16 + rb4;
      const int gn = n0 + wn + nf * 16 + fr;
      if constexpr (EPI == EP_QKV) {
        if (gn < 2048) {
          ushort* dst = (gn < 1024) ? (ushort*)O0 : (ushort*)O1;
          const int col = gn & 1023;
#pragma unroll
          for (int r = 0; r < 4; ++r)
            dst[(size_t)(gm0 + r) * 1024 + col] = f2bf(acc[mf][nf][r]);
        } else {  // v transposed: vT[b][d][t]
          const int d = gn - 2048, b = gm0 >> 11, ttp = gm0 & 2047;
          ushort4 w4;
          w4.x = f2bf(acc[mf][nf][0]); w4.y = f2bf(acc[mf][nf][1]);
          w4.z = f2bf(acc[mf][nf][2]); w4.w = f2bf(acc[mf][nf][3]);
          *(ushort4*)&((ushort*)O2)[(size_t)b * LD + (size_t)d * Ll + ttp] = w4;
        }
      } else {
#pragma unroll
        for (int r = 0; r < 4; ++r) {
          const int gm = gm0 + r;
          const size_t idx = (size_t)z * sC + (size_t)gm * ldc + gn;
          const float v = acc[mf][nf][r];
          if constexpr (EPI == EP_UG) {
            const float b = (gn < 2048) ? bias[gn] : bias2[gn - 2048];
            ((ushort*)O0)[idx] = f2bf(v + b);
          } else if constexpr (EPI == EP_DOWN) {
            ((ushort*)O0)[idx] = f2bf(v + bias[gn]);
          } else if constexpr (EPI == EP_DECAY) {
            ((ushort*)O0)[idx] =
                (gn <= gm) ? f2bf(v * __expf((float)(gm - gn) * logd)) : (ushort)0;
          } else if constexpr (EPI == EP_Y) {
            ((ushort*)O0)[idx] = f2bf(v);
          } else {  // EP_WO
            ((float*)O0)[idx] = v + xres[idx];
          }
        }
      }
    }
  }
}

// fp32 [R][C] -> bf16 [C][R]
__global__ __launch_bounds__(256) void transpose_bf16_k(
    const float* __restrict__ src, ushort* __restrict__ dst, int R, int C) {
  __shared__ float tile[32][33];
  const int c0 = blockIdx.x * 32, r0 = blockIdx.y * 32;
  const int tx = threadIdx.x, ty = threadIdx.y;
#pragma unroll
  for (int i = 0; i < 4; ++i)
    tile[ty + i * 8][tx] = src[(size_t)(r0 + ty + i * 8) * C + c0 + tx];
  __syncthreads();
#pragma unroll
  for (int i = 0; i < 4; ++i)
    dst[(size_t)(c0 + ty + i * 8) * R + r0 + tx] = f2bf(tile[tx][ty + i * 8]);
}

// conv_w [DI][4] fp32 -> cwT [4][DI] bf16
__global__ __launch_bounds__(256) void pack_convw_k(const float* __restrict__ cw,
                                                    ushort* __restrict__ cwT) {
  const int c = blockIdx.x * 256 + threadIdx.x;
  const float4 v = *(const float4*)(cw + c * 4);
  cwT[0 * DIc + c] = f2bf(v.x);
  cwT[1 * DIc + c] = f2bf(v.y);
  cwT[2 * DIc + c] = f2bf(v.z);
  cwT[3 * DIc + c] = f2bf(v.w);
}

__global__ __launch_bounds__(256) void rmsnorm_k(const float* __restrict__ x,
                                                 const float* __restrict__ w,
                                                 ushort* __restrict__ o) {
  const int row = blockIdx.x;
  const float* xr = x + (size_t)row * Dd;
  const int t = threadIdx.x;
  const float4 v = *(const float4*)(xr + t * 4);
  float ss = v.x * v.x + v.y * v.y + v.z * v.z + v.w * v.w;
#pragma unroll
  for (int m = 32; m; m >>= 1) ss += __shfl_xor(ss, m);
  __shared__ float red[4];
  if ((t & 63) == 0) red[t >> 6] = ss;
  __syncthreads();
  const float total = red[0] + red[1] + red[2] + red[3];
  const float rs = rsqrtf(total * (1.f / (float)Dd) + 1e-6f);
  const float4 wt = *(const float4*)(w + t * 4);
  ushort4 r;
  r.x = f2bf(v.x * rs * wt.x); r.y = f2bf(v.y * rs * wt.y);
  r.z = f2bf(v.z * rs * wt.z); r.w = f2bf(v.w * rs * wt.w);
  *(ushort4*)(o + (size_t)row * Dd + t * 4) = r;
}

// combined = silu(conv(up)+cb) * silu(gate); 8 ch x 8 t per thread
__global__ __launch_bounds__(256) void conv_gate_k(
    const ushort* __restrict__ ug, const ushort* __restrict__ cwT,
    const float* __restrict__ cb, ushort* __restrict__ o) {
  const int t = threadIdx.x;
  const int cg = t & 31;
  const int ts = t >> 5;
  const int cblk = blockIdx.x & 7;
  const int rblk = blockIdx.x >> 3;
  const int c = cblk * 256 + cg * 8;
  const int row0 = rblk * 64 + ts * 8;

  u16x8 w[4];
#pragma unroll
  for (int k = 0; k < 4; ++k) w[k] = *(const u16x8*)&cwT[k * DIc + c];
  float wb[8];
  *(float4*)&wb[0] = *(const float4*)(cb + c);
  *(float4*)&wb[4] = *(const float4*)(cb + c + 4);

  u16x8 h3, h2, h1;
  if ((row0 & (Ll - 1)) == 0) {
    h3 = (u16x8){}; h2 = (u16x8){}; h1 = (u16x8){};
  } else {
    h3 = *(const u16x8*)&ug[(size_t)(row0 - 3) * 4096 + c];
    h2 = *(const u16x8*)&ug[(size_t)(row0 - 2) * 4096 + c];
    h1 = *(const u16x8*)&ug[(size_t)(row0 - 1) * 4096 + c];
  }

#pragma unroll
  for (int i = 0; i < 8; ++i) {
    const size_t rbase = (size_t)(row0 + i) * 4096;
    const u16x8 h0 = *(const u16x8*)&ug[rbase + c];
    const u16x8 g  = *(const u16x8*)&ug[rbase + 2048 + c];
    u16x8 ov;
#pragma unroll
    for (int j = 0; j < 8; ++j) {
      float acc = wb[j];
      acc += bf2f(w[0][j]) * bf2f(h3[j]);
      acc += bf2f(w[1][j]) * bf2f(h2[j]);
      acc += bf2f(w[2][j]) * bf2f(h1[j]);
      acc += bf2f(w[3][j]) * bf2f(h0[j]);
      ov[j] = f2bf(silu(acc) * silu(bf2f(g[j])));
    }
    *(u16x8*)&o[(size_t)(row0 + i) * DIc + c] = ov;
    h3 = h2; h2 = h1; h1 = h0;
  }
}

extern "C" void kernel_launch(void* const* d_in, const int* in_sizes, int n_in,
                              void* d_out, int out_size, void* d_ws,
                              size_t ws_size, hipStream_t stream) {
  const float* x      = (const float*)d_in[0];
  const float* norm_w = (const float*)d_in[1];
  const float* up_w   = (const float*)d_in[2];
  const float* up_b   = (const float*)d_in[3];
  const float* gate_w = (const float*)d_in[4];
  const float* gate_b = (const float*)d_in[5];
  const float* down_w = (const float*)d_in[6];
  const float* down_b = (const float*)d_in[7];
  const float* conv_w = (const float*)d_in[8];
  const float* conv_b = (const float*)d_in[9];
  const float* wq     = (const float*)d_in[10];
  const float* wk     = (const float*)d_in[11];
  const float* wv     = (const float*)d_in[12];
  const float* wo     = (const float*)d_in[13];
  const float* decay  = (const float*)d_in[14];
  float* out = (float*)d_out;
  char* w8 = (char*)d_ws;

  const size_t MiB = 1u << 20;
  ushort* nrm      = (ushort*)(w8 + 0 * MiB);    // 16: normed, later down-out
  ushort* ug       = (ushort*)(w8 + 16 * MiB);   // 64: up|gate [8192][4096]
  ushort* S        = (ushort*)(w8 + 16 * MiB);   // 32 (aliases ug; disjoint life)
  ushort* combined = (ushort*)(w8 + 80 * MiB);   // 32
  ushort* buf1     = (ushort*)(w8 + 112 * MiB);  // 32: q|k
  ushort* buf2     = (ushort*)(w8 + 144 * MiB);  // 32: vT|y
  ushort* ugw      = (ushort*)(w8 + 176 * MiB);  // 8: [4096][1024]
  ushort* down_wT  = (ushort*)(w8 + 184 * MiB);  // 4: [1024][2048]
  ushort* qkv_wT   = (ushort*)(w8 + 188 * MiB);  // 6: [3072][1024]
  ushort* wo_T     = (ushort*)(w8 + 194 * MiB);  // 2
  ushort* cwT      = (ushort*)(w8 + 196 * MiB);  // 16 KiB

  ushort* q  = buf1;
  ushort* kb = buf1 + BLD;
  ushort* vT = buf2;
  ushort* y  = buf2 + BLD;

  const dim3 tb(32, 8);
  transpose_bf16_k<<<dim3(64, 32), tb, 0, stream>>>(up_w, ugw, 1024, 2048);
  transpose_bf16_k<<<dim3(64, 32), tb, 0, stream>>>(gate_w, ugw + 2048 * 1024, 1024, 2048);
  transpose_bf16_k<<<dim3(32, 64), tb, 0, stream>>>(down_w, down_wT, 2048, 1024);
  transpose_bf16_k<<<dim3(32, 32), tb, 0, stream>>>(wq, qkv_wT, 1024, 1024);
  transpose_bf16_k<<<dim3(32, 32), tb, 0, stream>>>(wk, qkv_wT + 1024 * 1024, 1024, 1024);
  transpose_bf16_k<<<dim3(32, 32), tb, 0, stream>>>(wv, qkv_wT + 2 * 1024 * 1024, 1024, 1024);
  transpose_bf16_k<<<dim3(32, 32), tb, 0, stream>>>(wo, wo_T, 1024, 1024);
  pack_convw_k<<<8, 256, 0, stream>>>(conv_w, cwT);

  rmsnorm_k<<<Bb * Ll, 256, 0, stream>>>(x, norm_w, nrm);

  // ug = normed @ [up_w|gate_w] + biases
  gemm8_k<EP_UG><<<dim3(16, 32), 512, 0, stream>>>(
      nrm, ugw, ug, up_b, gate_b, nullptr, nullptr,
      1024, 1024, 1024, 4096, 0, 0, 0, nullptr, nullptr);

  conv_gate_k<<<1024, 256, 0, stream>>>(ug, cwT, conv_b, combined);

  // down-out = combined @ down_w + b   (into nrm)
  gemm8_k<EP_DOWN><<<dim3(4, 32), 512, 0, stream>>>(
      combined, down_wT, nrm, down_b, nullptr, nullptr, nullptr,
      2048, 2048, 2048, 1024, 0, 0, 0, nullptr, nullptr);

  // q|k|vT = down-out @ [wq|wk|wv]
  gemm8_k<EP_QKV><<<dim3(12, 32), 512, 0, stream>>>(
      nrm, qkv_wT, q, nullptr, nullptr, nullptr, nullptr,
      1024, 1024, 1024, 1024, 0, 0, 0, kb, vT);

  // S = tril(q k^T) * d^(t-s)
  gemm8_k<EP_DECAY><<<dim3(8, 8, Bb), 512, 0, stream>>>(
      q, kb, S, nullptr, nullptr, nullptr, decay,
      1024, 1024, 1024, 2048, LD, LD, (long)Ll * Ll, nullptr, nullptr);

  // y = S @ v  (K clamped to m0+256 by causality)
  gemm8_k<EP_Y><<<dim3(4, 8, Bb), 512, 0, stream>>>(
      S, vT, y, nullptr, nullptr, nullptr, nullptr,
      2048, 2048, 2048, 1024, (long)Ll * Ll, LD, LD, nullptr, nullptr);

  // out = x + y @ wo
  gemm8_k<EP_WO><<<dim3(4, 32), 512, 0, stream>>>(
      y, wo_T, out, nullptr, nullptr, x, nullptr,
      1024, 1024, 1024, 1024, 0, 0, 0, nullptr, nullptr);
}

// Round 5
// 323.728 us; speedup vs baseline: 3.6201x; 1.1785x over previous
//
#include <hip/hip_runtime.h>

// Fused block, all-bf16 dataflow. GEMMs: 8-phase template, BN=256, BK=64,
// 8 waves, st_16x32 LDS swizzle, counted vmcnt, setprio. Two tile heights:
// BM=256 (8-phase/2-tiles, 128 KiB LDS) and BM=128 (4-phase/2-tiles, 96 KiB
// LDS) so every dispatch grid is an exact multiple of 256 CUs.
// Decay-memory scan computed as causal masked attention (QK^T * d^(t-s)) @ V.

typedef __bf16 bf16x8 __attribute__((ext_vector_type(8)));
typedef unsigned short u16x8 __attribute__((ext_vector_type(8)));
typedef float f32x4 __attribute__((ext_vector_type(4)));

constexpr int Bb = 4, Ll = 2048, Dd = 1024, DIc = 2048;
constexpr long LD  = (long)Ll * Dd;   // 2,097,152
constexpr long BLD = (long)Bb * LD;   // 8,388,608

static __device__ __forceinline__ unsigned short f2bf(float f) {
  unsigned u = __builtin_bit_cast(unsigned, f);
  u += 0x7fffu + ((u >> 16) & 1u);  // RNE
  return (unsigned short)(u >> 16);
}
static __device__ __forceinline__ float bf2f(unsigned short u) {
  return __builtin_bit_cast(float, (unsigned)u << 16);
}
static __device__ __forceinline__ float silu(float g) {
  return g / (1.f + __expf(-g));
}

enum { EP_UG = 0, EP_DOWN, EP_QKV, EP_DECAY, EP_Y, EP_WO };

// LDS map (ushort idx): A: dbuf*ADB + kh*AKH + subtile*512
//                       B: BOFF + dbuf*16384 + kh*8192 + subtile*512
#define STAGE_A(DBUF, MG, KH, TILE) {                                          \
    const int kt_ = ((TILE) < NTm1 ? (TILE) : NTm1);                           \
    __builtin_amdgcn_global_load_lds(                                          \
      (const __attribute__((address_space(1))) void*)                          \
        (Ag + (size_t)(aRow + (MG)*64) * lda + kt_*64 + (KH)*32 + aCol),       \
      (__attribute__((address_space(3))) void*)                                \
        (lds + (DBUF)*ADB + (KH)*AKH + (aRb + (MG)*4)*512), 16, 0, 0); }

#define STAGE_B(DBUF, NH, KH, TILE) {                                          \
    const int kt_ = ((TILE) < NTm1 ? (TILE) : NTm1);                           \
    __builtin_amdgcn_global_load_lds(                                          \
      (const __attribute__((address_space(1))) void*)                          \
        (Bg + (size_t)(bRow + (NH)*128) * ldb + kt_*64 + (KH)*32 + aCol),      \
      (__attribute__((address_space(3))) void*)                                \
        (lds + BOFF + (DBUF)*16384 + (KH)*8192 + ((NH)*8 + w)*512), 16, 0, 0); }

#define LOAD_A(DBUF, KS, MG) {                                                 \
  _Pragma("unroll") for (int j_ = 0; j_ < 4; ++j_)                             \
    af[j_] = *(const bf16x8*)&lds[(DBUF)*ADB + (KS)*AKH +                      \
        (aRdBase + (MG)*4 + j_)*512 + fr*32 + cph]; }

#define LOAD_B(DBUF, KS) {                                                     \
  _Pragma("unroll") for (int n_ = 0; n_ < 4; ++n_)                             \
    bfr[KS][n_] = *(const bf16x8*)&lds[BOFF + (DBUF)*16384 + (KS)*8192 +       \
        (bRb + n_)*512 + fr*32 + cph]; }

#define MFMA_PH(KS, MG) {                                                      \
  __builtin_amdgcn_s_setprio(1);                                               \
  _Pragma("unroll") for (int j_ = 0; j_ < 4; ++j_)                             \
  _Pragma("unroll") for (int n_ = 0; n_ < 4; ++n_)                             \
    acc[(MG)*4 + j_][n_] = __builtin_amdgcn_mfma_f32_16x16x32_bf16(            \
        af[j_], bfr[KS][n_], acc[(MG)*4 + j_][n_], 0, 0, 0);                   \
  __builtin_amdgcn_s_setprio(0); }

#define BAR() __builtin_amdgcn_s_barrier()
#define WAIT_LGKM0() { asm volatile("s_waitcnt lgkmcnt(0)" ::: "memory");      \
                       __builtin_amdgcn_sched_barrier(0); }
#define WAIT_LGKM8() asm volatile("s_waitcnt lgkmcnt(8)" ::: "memory")
#define WAIT_VM(N) asm volatile("s_waitcnt vmcnt(" #N ")" ::: "memory")

template <int EPI, int BM>
__global__ __launch_bounds__(512, 2) void gemm8_k(
    const ushort* __restrict__ A, const ushort* __restrict__ Bm,
    void* __restrict__ O0, const float* __restrict__ bias,
    const float* __restrict__ bias2, const float* __restrict__ xres,
    const float* __restrict__ decayp,
    int K, int lda, int ldb, int ldc,
    long sA, long sB, long sC,
    void* __restrict__ O1, void* __restrict__ O2) {
  constexpr int MF = BM / 32;          // m-frags per wave
  constexpr int ADB = BM * 64;         // A ushorts per dbuf
  constexpr int AKH = BM * 32;         // A ushorts per k-half
  constexpr int BOFF = BM * 128;       // B region base
  __shared__ ushort lds[BM == 256 ? 65536 : 49152];

  const int z = blockIdx.z;
  const int gx = gridDim.x;
  const int nwg = gx * gridDim.y;
  const int id = blockIdx.y * gx + blockIdx.x;
  const int chunk = nwg >> 3;
  const int swz = (id & 7) * chunk + (id >> 3);
  const int m0 = (swz / gx) * BM;
  const int n0 = (swz % gx) * 256;

  const int t = threadIdx.x;
  const int lane = t & 63;
  const int w = t >> 6;

  if constexpr (EPI == EP_DECAY) {
    if (n0 > m0) {  // fully above diagonal: zero-fill
      ushort* S = (ushort*)O0 + (size_t)z * sC;
      u16x8 zz = {};
#pragma unroll
      for (int i = 0; i < BM / 16; ++i) {
        const int cid = i * 512 + t;
        *(u16x8*)&S[(size_t)(m0 + (cid >> 5)) * ldc + n0 + (cid & 31) * 8] = zz;
      }
      return;
    }
  }

  const ushort* Ag = A + (size_t)z * sA + (size_t)m0 * lda;
  const ushort* Bg = Bm + (size_t)z * sB + (size_t)n0 * ldb;

  int Kend = K;
  if constexpr (EPI == EP_Y) Kend = (K < m0 + BM) ? K : m0 + BM;
  const int NT = Kend >> 6;
  const int NTm1 = NT - 1;
  const int NI = NT >> 1;

  // stage-side: lane' pre-applies the st_16x32 swizzle
  const int lp = lane ^ (((lane >> 5) & 1) << 1);
  const int aCol = (lp & 3) * 8;
  const int bRow = (w >> 2) * 64 + (w & 3) * 16 + (lp >> 2);
  int aRow, aRb, aRdBase;
  if constexpr (BM == 256) {
    aRow = (w >> 2) * 128 + (w & 3) * 16 + (lp >> 2);
    aRb = (w >> 2) * 8 + (w & 3);
    aRdBase = (w >> 2) * 8;
  } else {
    aRow = w * 16 + (lp >> 2);
    aRb = w;
    aRdBase = (w >> 2) * 4;
  }
  // read-side
  const int fr = lane & 15;
  const int kg = (lane >> 4) * 8;
  const int cph = kg ^ (((fr >> 3) & 1) << 4);
  const int bRb = ((w & 3) >> 1) * 8 + ((w & 3) & 1) * 4;

  f32x4 acc[MF][4] = {};
  bf16x8 af[4], bfr[2][4];

  if constexpr (BM == 256) {
    // prologue: tile0 full (8) + tile1 B(4) + A(mg0)(2)
    STAGE_A(0, 0, 0, 0); STAGE_A(0, 0, 1, 0); STAGE_A(0, 1, 0, 0); STAGE_A(0, 1, 1, 0);
    STAGE_B(0, 0, 0, 0); STAGE_B(0, 0, 1, 0); STAGE_B(0, 1, 0, 0); STAGE_B(0, 1, 1, 0);
    STAGE_B(1, 0, 0, 1); STAGE_B(1, 0, 1, 1); STAGE_B(1, 1, 0, 1); STAGE_B(1, 1, 1, 1);
    STAGE_A(1, 0, 0, 1); STAGE_A(1, 0, 1, 1);
    WAIT_VM(6);
    BAR();
    for (int i = 0; i < NI; ++i) {
      const int tt = 2 * i;
      LOAD_B(0, 0); LOAD_B(0, 1); LOAD_A(0, 0, 0);
      STAGE_A(1, 1, 0, tt + 1); STAGE_A(1, 1, 1, tt + 1);
      WAIT_LGKM8();
      BAR(); WAIT_LGKM0();
      MFMA_PH(0, 0);
      BAR();
      LOAD_A(0, 0, 1);
      STAGE_B(0, 0, 0, tt + 2); STAGE_B(0, 1, 0, tt + 2);
      BAR(); WAIT_LGKM0();
      MFMA_PH(0, 1);
      BAR();
      LOAD_A(0, 1, 0);
      STAGE_B(0, 0, 1, tt + 2); STAGE_B(0, 1, 1, tt + 2);
      BAR(); WAIT_LGKM0();
      MFMA_PH(1, 0);
      BAR();
      LOAD_A(0, 1, 1);
      STAGE_A(0, 0, 0, tt + 2); STAGE_A(0, 0, 1, tt + 2);
      WAIT_VM(6);
      BAR(); WAIT_LGKM0();
      MFMA_PH(1, 1);
      BAR();
      LOAD_B(1, 0); LOAD_B(1, 1); LOAD_A(1, 0, 0);
      STAGE_A(0, 1, 0, tt + 2); STAGE_A(0, 1, 1, tt + 2);
      WAIT_LGKM8();
      BAR(); WAIT_LGKM0();
      MFMA_PH(0, 0);
      BAR();
      LOAD_A(1, 0, 1);
      STAGE_B(1, 0, 0, tt + 3); STAGE_B(1, 1, 0, tt + 3);
      BAR(); WAIT_LGKM0();
      MFMA_PH(0, 1);
      BAR();
      LOAD_A(1, 1, 0);
      STAGE_B(1, 0, 1, tt + 3); STAGE_B(1, 1, 1, tt + 3);
      BAR(); WAIT_LGKM0();
      MFMA_PH(1, 0);
      BAR();
      LOAD_A(1, 1, 1);
      STAGE_A(1, 0, 0, tt + 3); STAGE_A(1, 0, 1, tt + 3);
      WAIT_VM(6);
      BAR(); WAIT_LGKM0();
      MFMA_PH(1, 1);
      BAR();
    }
  } else {
    // BM=128: 4 phases per 2 tiles. Per tile: A=2 stage units, B=4.
    // prologue: A[0](2) + B[0](4) + B[1](4); allow B[1] outstanding.
    STAGE_A(0, 0, 0, 0); STAGE_A(0, 0, 1, 0);
    STAGE_B(0, 0, 0, 0); STAGE_B(0, 1, 0, 0); STAGE_B(0, 0, 1, 0); STAGE_B(0, 1, 1, 0);
    STAGE_B(1, 0, 0, 1); STAGE_B(1, 1, 0, 1); STAGE_B(1, 0, 1, 1); STAGE_B(1, 1, 1, 1);
    WAIT_VM(4);
    BAR();
    for (int i = 0; i < NI; ++i) {
      const int tt = 2 * i;
      // ph1 (tile tt, buf0, ks0) | stage A[tt+1] -> buf1
      LOAD_B(0, 0); LOAD_B(0, 1); LOAD_A(0, 0, 0);
      STAGE_A(1, 0, 0, tt + 1); STAGE_A(1, 0, 1, tt + 1);
      WAIT_LGKM8();
      BAR(); WAIT_LGKM0();
      MFMA_PH(0, 0);
      BAR();
      // ph2 (ks1) | stage B[tt+2] -> buf0; vmcnt(4) forces A[tt+1],B[tt+1]
      LOAD_A(0, 1, 0);
      STAGE_B(0, 0, 0, tt + 2); STAGE_B(0, 1, 0, tt + 2);
      STAGE_B(0, 0, 1, tt + 2); STAGE_B(0, 1, 1, tt + 2);
      WAIT_VM(4);
      BAR(); WAIT_LGKM0();
      MFMA_PH(1, 0);
      BAR();
      // ph3 (tile tt+1, buf1, ks0) | stage A[tt+2] -> buf0
      LOAD_B(1, 0); LOAD_B(1, 1); LOAD_A(1, 0, 0);
      STAGE_A(0, 0, 0, tt + 2); STAGE_A(0, 0, 1, tt + 2);
      WAIT_LGKM8();
      BAR(); WAIT_LGKM0();
      MFMA_PH(0, 0);
      BAR();
      // ph4 (ks1) | stage B[tt+3] -> buf1; vmcnt(4) forces A[tt+2],B[tt+2]
      LOAD_A(1, 1, 0);
      STAGE_B(1, 0, 0, tt + 3); STAGE_B(1, 1, 0, tt + 3);
      STAGE_B(1, 0, 1, tt + 3); STAGE_B(1, 1, 1, tt + 3);
      WAIT_VM(4);
      BAR(); WAIT_LGKM0();
      MFMA_PH(1, 0);
      BAR();
    }
  }

  // ---- epilogue ---- C/D: col=lane&15, row=(lane>>4)*4+reg
  const int rb4 = (lane >> 4) * 4;
  const int wm = (w >> 2) * (BM / 2), wn = (w & 3) * 64;
  float logd = 0.f;
  if constexpr (EPI == EP_DECAY) logd = __logf(decayp[0]);

#pragma unroll
  for (int mf = 0; mf < MF; ++mf) {
#pragma unroll
    for (int nf = 0; nf < 4; ++nf) {
      const int gm0 = m0 + wm + mf * 16 + rb4;
      const int gn = n0 + wn + nf * 16 + fr;
      if constexpr (EPI == EP_QKV) {
        if (gn < 2048) {
          ushort* dst = (gn < 1024) ? (ushort*)O0 : (ushort*)O1;
          const int col = gn & 1023;
#pragma unroll
          for (int r = 0; r < 4; ++r)
            dst[(size_t)(gm0 + r) * 1024 + col] = f2bf(acc[mf][nf][r]);
        } else {  // v transposed: vT[b][d][t]
          const int d = gn - 2048, b = gm0 >> 11, ttp = gm0 & 2047;
          ushort4 w4;
          w4.x = f2bf(acc[mf][nf][0]); w4.y = f2bf(acc[mf][nf][1]);
          w4.z = f2bf(acc[mf][nf][2]); w4.w = f2bf(acc[mf][nf][3]);
          *(ushort4*)&((ushort*)O2)[(size_t)b * LD + (size_t)d * Ll + ttp] = w4;
        }
      } else {
#pragma unroll
        for (int r = 0; r < 4; ++r) {
          const int gm = gm0 + r;
          const size_t idx = (size_t)z * sC + (size_t)gm * ldc + gn;
          const float v = acc[mf][nf][r];
          if constexpr (EPI == EP_UG) {
            const float b = (gn < 2048) ? bias[gn] : bias2[gn - 2048];
            ((ushort*)O0)[idx] = f2bf(v + b);
          } else if constexpr (EPI == EP_DOWN) {
            ((ushort*)O0)[idx] = f2bf(v + bias[gn]);
          } else if constexpr (EPI == EP_DECAY) {
            ((ushort*)O0)[idx] =
                (gn <= gm) ? f2bf(v * __expf((float)(gm - gn) * logd)) : (ushort)0;
          } else if constexpr (EPI == EP_Y) {
            ((ushort*)O0)[idx] = f2bf(v);
          } else {  // EP_WO
            ((float*)O0)[idx] = v + xres[idx];
          }
        }
      }
    }
  }
}

// One launch for all prep: 7 weight transposes + conv pack + rmsnorm.
__global__ __launch_bounds__(256) void prep_k(
    const float* __restrict__ up_w, const float* __restrict__ gate_w,
    const float* __restrict__ down_w, const float* __restrict__ wq,
    const float* __restrict__ wk, const float* __restrict__ wv,
    const float* __restrict__ wo, const float* __restrict__ conv_w,
    const float* __restrict__ x, const float* __restrict__ norm_w,
    ushort* __restrict__ ugw, ushort* __restrict__ down_wT,
    ushort* __restrict__ qkv_wT, ushort* __restrict__ wo_T,
    ushort* __restrict__ cwT, ushort* __restrict__ nrm) {
  const int bid = blockIdx.x;
  const int t = threadIdx.x;
  if (bid < 10240) {  // transpose segments: fp32 [R][C] -> bf16 [C][R]
    const float* src; ushort* dst; int R, C, idx;
    if (bid < 2048)      { src = up_w;   dst = ugw;                R = 1024; C = 2048; idx = bid; }
    else if (bid < 4096) { src = gate_w; dst = ugw + 2048 * 1024;  R = 1024; C = 2048; idx = bid - 2048; }
    else if (bid < 6144) { src = down_w; dst = down_wT;            R = 2048; C = 1024; idx = bid - 4096; }
    else if (bid < 7168) { src = wq;     dst = qkv_wT;             R = 1024; C = 1024; idx = bid - 6144; }
    else if (bid < 8192) { src = wk;     dst = qkv_wT + 1024*1024; R = 1024; C = 1024; idx = bid - 7168; }
    else if (bid < 9216) { src = wv;     dst = qkv_wT + 2*1024*1024; R = 1024; C = 1024; idx = bid - 8192; }
    else                 { src = wo;     dst = wo_T;               R = 1024; C = 1024; idx = bid - 9216; }
    __shared__ float tile[32][33];
    const int tx = t & 31, ty = t >> 5;
    const int tilesx = C >> 5;
    const int c0 = (idx % tilesx) * 32, r0 = (idx / tilesx) * 32;
#pragma unroll
    for (int i = 0; i < 4; ++i)
      tile[ty + i * 8][tx] = src[(size_t)(r0 + ty + i * 8) * C + c0 + tx];
    __syncthreads();
#pragma unroll
    for (int i = 0; i < 4; ++i)
      dst[(size_t)(c0 + ty + i * 8) * R + r0 + tx] = f2bf(tile[tx][ty + i * 8]);
  } else if (bid < 10248) {  // conv_w [DI][4] -> cwT [4][DI]
    const int c = (bid - 10240) * 256 + t;
    const float4 v = *(const float4*)(conv_w + c * 4);
    cwT[0 * DIc + c] = f2bf(v.x);
    cwT[1 * DIc + c] = f2bf(v.y);
    cwT[2 * DIc + c] = f2bf(v.z);
    cwT[3 * DIc + c] = f2bf(v.w);
  } else {  // rmsnorm rows
    const int row = bid - 10248;
    const float* xr = x + (size_t)row * Dd;
    const float4 v = *(const float4*)(xr + t * 4);
    float ss = v.x * v.x + v.y * v.y + v.z * v.z + v.w * v.w;
#pragma unroll
    for (int m = 32; m; m >>= 1) ss += __shfl_xor(ss, m);
    __shared__ float red[4];
    if ((t & 63) == 0) red[t >> 6] = ss;
    __syncthreads();
    const float total = red[0] + red[1] + red[2] + red[3];
    const float rs = rsqrtf(total * (1.f / (float)Dd) + 1e-6f);
    const float4 wt = *(const float4*)(norm_w + t * 4);
    ushort4 r;
    r.x = f2bf(v.x * rs * wt.x); r.y = f2bf(v.y * rs * wt.y);
    r.z = f2bf(v.z * rs * wt.z); r.w = f2bf(v.w * rs * wt.w);
    *(ushort4*)(nrm + (size_t)row * Dd + t * 4) = r;
  }
}

// combined = silu(conv(up)+cb) * silu(gate); 8 ch x 8 t per thread
__global__ __launch_bounds__(256) void conv_gate_k(
    const ushort* __restrict__ ug, const ushort* __restrict__ cwT,
    const float* __restrict__ cb, ushort* __restrict__ o) {
  const int t = threadIdx.x;
  const int cg = t & 31;
  const int ts = t >> 5;
  const int cblk = blockIdx.x & 7;
  const int rblk = blockIdx.x >> 3;
  const int c = cblk * 256 + cg * 8;
  const int row0 = rblk * 64 + ts * 8;

  u16x8 w[4];
#pragma unroll
  for (int k = 0; k < 4; ++k) w[k] = *(const u16x8*)&cwT[k * DIc + c];
  float wb[8];
  *(float4*)&wb[0] = *(const float4*)(cb + c);
  *(float4*)&wb[4] = *(const float4*)(cb + c + 4);

  u16x8 h3, h2, h1;
  if ((row0 & (Ll - 1)) == 0) {
    h3 = (u16x8){}; h2 = (u16x8){}; h1 = (u16x8){};
  } else {
    h3 = *(const u16x8*)&ug[(size_t)(row0 - 3) * 4096 + c];
    h2 = *(const u16x8*)&ug[(size_t)(row0 - 2) * 4096 + c];
    h1 = *(const u16x8*)&ug[(size_t)(row0 - 1) * 4096 + c];
  }

#pragma unroll
  for (int i = 0; i < 8; ++i) {
    const size_t rbase = (size_t)(row0 + i) * 4096;
    const u16x8 h0 = *(const u16x8*)&ug[rbase + c];
    const u16x8 g  = *(const u16x8*)&ug[rbase + 2048 + c];
    u16x8 ov;
#pragma unroll
    for (int j = 0; j < 8; ++j) {
      float acc = wb[j];
      acc += bf2f(w[0][j]) * bf2f(h3[j]);
      acc += bf2f(w[1][j]) * bf2f(h2[j]);
      acc += bf2f(w[2][j]) * bf2f(h1[j]);
      acc += bf2f(w[3][j]) * bf2f(h0[j]);
      ov[j] = f2bf(silu(acc) * silu(bf2f(g[j])));
    }
    *(u16x8*)&o[(size_t)(row0 + i) * DIc + c] = ov;
    h3 = h2; h2 = h1; h1 = h0;
  }
}

extern "C" void kernel_launch(void* const* d_in, const int* in_sizes, int n_in,
                              void* d_out, int out_size, void* d_ws,
                              size_t ws_size, hipStream_t stream) {
  const float* x      = (const float*)d_in[0];
  const float* norm_w = (const float*)d_in[1];
  const float* up_w   = (const float*)d_in[2];
  const float* up_b   = (const float*)d_in[3];
  const float* gate_w = (const float*)d_in[4];
  const float* gate_b = (const float*)d_in[5];
  const float* down_w = (const float*)d_in[6];
  const float* down_b = (const float*)d_in[7];
  const float* conv_w = (const float*)d_in[8];
  const float* conv_b = (const float*)d_in[9];
  const float* wq     = (const float*)d_in[10];
  const float* wk     = (const float*)d_in[11];
  const float* wv     = (const float*)d_in[12];
  const float* wo     = (const float*)d_in[13];
  const float* decay  = (const float*)d_in[14];
  float* out = (float*)d_out;
  char* w8 = (char*)d_ws;

  const size_t MiB = 1u << 20;
  ushort* nrm      = (ushort*)(w8 + 0 * MiB);    // 16: normed, later down-out
  ushort* ug       = (ushort*)(w8 + 16 * MiB);   // 64: up|gate [8192][4096]
  ushort* S        = (ushort*)(w8 + 16 * MiB);   // 32 (aliases ug; disjoint life)
  ushort* combined = (ushort*)(w8 + 80 * MiB);   // 32
  ushort* buf1     = (ushort*)(w8 + 112 * MiB);  // 32: q|k
  ushort* buf2     = (ushort*)(w8 + 144 * MiB);  // 32: vT|y
  ushort* ugw      = (ushort*)(w8 + 176 * MiB);  // 8: [4096][1024]
  ushort* down_wT  = (ushort*)(w8 + 184 * MiB);  // 4: [1024][2048]
  ushort* qkv_wT   = (ushort*)(w8 + 188 * MiB);  // 6: [3072][1024]
  ushort* wo_T     = (ushort*)(w8 + 194 * MiB);  // 2
  ushort* cwT      = (ushort*)(w8 + 196 * MiB);  // 16 KiB

  ushort* q  = buf1;
  ushort* kb = buf1 + BLD;
  ushort* vT = buf2;
  ushort* y  = buf2 + BLD;

  // all prep (7 transposes + conv pack + rmsnorm) in one launch
  prep_k<<<18440, 256, 0, stream>>>(up_w, gate_w, down_w, wq, wk, wv, wo,
                                    conv_w, x, norm_w,
                                    ugw, down_wT, qkv_wT, wo_T, cwT, nrm);

  // ug = normed @ [up_w|gate_w] + biases         (512 blocks = 2.0 waves)
  gemm8_k<EP_UG, 256><<<dim3(16, 32), 512, 0, stream>>>(
      nrm, ugw, ug, up_b, gate_b, nullptr, nullptr,
      1024, 1024, 1024, 4096, 0, 0, 0, nullptr, nullptr);

  conv_gate_k<<<1024, 256, 0, stream>>>(ug, cwT, conv_b, combined);

  // down-out = combined @ down_w + b             (256 blocks = 1.0)
  gemm8_k<EP_DOWN, 128><<<dim3(4, 64), 512, 0, stream>>>(
      combined, down_wT, nrm, down_b, nullptr, nullptr, nullptr,
      2048, 2048, 2048, 1024, 0, 0, 0, nullptr, nullptr);

  // q|k|vT = down-out @ [wq|wk|wv]               (768 blocks = 3.0)
  gemm8_k<EP_QKV, 128><<<dim3(12, 64), 512, 0, stream>>>(
      nrm, qkv_wT, q, nullptr, nullptr, nullptr, nullptr,
      1024, 1024, 1024, 1024, 0, 0, 0, kb, vT);

  // S = tril(q k^T) * d^(t-s)                    (256 blocks = 1.0)
  gemm8_k<EP_DECAY, 256><<<dim3(8, 8, Bb), 512, 0, stream>>>(
      q, kb, S, nullptr, nullptr, nullptr, decay,
      1024, 1024, 1024, 2048, LD, LD, (long)Ll * Ll, nullptr, nullptr);

  // y = S @ v  (K clamped to m0+128 by causality) (256 blocks = 1.0)
  gemm8_k<EP_Y, 128><<<dim3(4, 16, Bb), 512, 0, stream>>>(
      S, vT, y, nullptr, nullptr, nullptr, nullptr,
      2048, 2048, 2048, 1024, (long)Ll * Ll, LD, LD, nullptr, nullptr);

  // out = x + y @ wo                             (256 blocks = 1.0)
  gemm8_k<EP_WO, 128><<<dim3(4, 64), 512, 0, stream>>>(
      y, wo_T, out, nullptr, nullptr, x, nullptr,
      1024, 1024, 1024, 1024, 0, 0, 0, nullptr, nullptr);
}

// Round 6
// 322.322 us; speedup vs baseline: 3.6358x; 1.0044x over previous
//
#include <hip/hip_runtime.h>

// Fused block, all-bf16 dataflow, 8-phase GEMM template (BN=256, BK=64, 8
// waves, st_16x32 LDS swizzle, counted vmcnt, setprio), BM=256 and BM=128.
// Algebraic folds: S = (D@W_qk)@D^T  (W_qk = wq wk^T), and wo folded into v:
// v' = D@(wv wo), out = x + S@v'. The two 1024^3 weight-product GEMMs ride as
// 32 extra blocks (z=1) on the UG dispatch.

typedef __bf16 bf16x8 __attribute__((ext_vector_type(8)));
typedef unsigned short u16x8 __attribute__((ext_vector_type(8)));
typedef float f32x4 __attribute__((ext_vector_type(4)));

constexpr int Bb = 4, Ll = 2048, Dd = 1024, DIc = 2048;
constexpr long LD  = (long)Ll * Dd;   // 2,097,152
constexpr long BLD = (long)Bb * LD;   // 8,388,608

static __device__ __forceinline__ unsigned short f2bf(float f) {
  unsigned u = __builtin_bit_cast(unsigned, f);
  u += 0x7fffu + ((u >> 16) & 1u);  // RNE
  return (unsigned short)(u >> 16);
}
static __device__ __forceinline__ float bf2f(unsigned short u) {
  return __builtin_bit_cast(float, (unsigned)u << 16);
}
static __device__ __forceinline__ float silu(float g) {
  return g / (1.f + __expf(-g));
}

enum { EP_UG = 0, EP_DOWN, EP_GV, EP_DECAY, EP_YO };

#define STAGE_A(DBUF, MG, KH, TILE) {                                          \
    const int kt_ = ((TILE) < NTm1 ? (TILE) : NTm1);                           \
    __builtin_amdgcn_global_load_lds(                                          \
      (const __attribute__((address_space(1))) void*)                          \
        (Ag + (size_t)(aRow + (MG)*64) * lda + kt_*64 + (KH)*32 + aCol),       \
      (__attribute__((address_space(3))) void*)                                \
        (lds + (DBUF)*ADB + (KH)*AKH + (aRb + (MG)*4)*512), 16, 0, 0); }

#define STAGE_B(DBUF, NH, KH, TILE) {                                          \
    const int kt_ = ((TILE) < NTm1 ? (TILE) : NTm1);                           \
    __builtin_amdgcn_global_load_lds(                                          \
      (const __attribute__((address_space(1))) void*)                          \
        (Bg + (size_t)(bRow + (NH)*128) * ldb + kt_*64 + (KH)*32 + aCol),      \
      (__attribute__((address_space(3))) void*)                                \
        (lds + BOFF + (DBUF)*16384 + (KH)*8192 + ((NH)*8 + w)*512), 16, 0, 0); }

#define LOAD_A(DBUF, KS, MG) {                                                 \
  _Pragma("unroll") for (int j_ = 0; j_ < 4; ++j_)                             \
    af[j_] = *(const bf16x8*)&lds[(DBUF)*ADB + (KS)*AKH +                      \
        (aRdBase + (MG)*4 + j_)*512 + fr*32 + cph]; }

#define LOAD_B(DBUF, KS) {                                                     \
  _Pragma("unroll") for (int n_ = 0; n_ < 4; ++n_)                             \
    bfr[KS][n_] = *(const bf16x8*)&lds[BOFF + (DBUF)*16384 + (KS)*8192 +       \
        (bRb + n_)*512 + fr*32 + cph]; }

#define MFMA_PH(KS, MG) {                                                      \
  __builtin_amdgcn_s_setprio(1);                                               \
  _Pragma("unroll") for (int j_ = 0; j_ < 4; ++j_)                             \
  _Pragma("unroll") for (int n_ = 0; n_ < 4; ++n_)                             \
    acc[(MG)*4 + j_][n_] = __builtin_amdgcn_mfma_f32_16x16x32_bf16(            \
        af[j_], bfr[KS][n_], acc[(MG)*4 + j_][n_], 0, 0, 0);                   \
  __builtin_amdgcn_s_setprio(0); }

#define BAR() __builtin_amdgcn_s_barrier()
#define WAIT_LGKM0() { asm volatile("s_waitcnt lgkmcnt(0)" ::: "memory");      \
                       __builtin_amdgcn_sched_barrier(0); }
#define WAIT_LGKM8() asm volatile("s_waitcnt lgkmcnt(8)" ::: "memory")
#define WAIT_VM(N) asm volatile("s_waitcnt vmcnt(" #N ")" ::: "memory")

template <int EPI, int BM>
__global__ __launch_bounds__(512, 2) void gemm8_k(
    const ushort* __restrict__ A, const ushort* __restrict__ Bm,
    void* __restrict__ O0, const float* __restrict__ bias,
    const float* __restrict__ bias2, const float* __restrict__ xres,
    const float* __restrict__ decayp,
    int K, int lda, int ldb, int ldc,
    long sA, long sB, long sC,
    void* __restrict__ O1,
    const ushort* __restrict__ sA1, const ushort* __restrict__ sB1,
    ushort* __restrict__ sC1,
    const ushort* __restrict__ sA2, const ushort* __restrict__ sB2,
    ushort* __restrict__ sC2) {
  constexpr int MF = BM / 32;
  constexpr int ADB = BM * 64;
  constexpr int AKH = BM * 32;
  constexpr int BOFF = BM * 128;
  __shared__ ushort lds[BM == 256 ? 65536 : 49152];

  const int z = blockIdx.z;
  const int gx = gridDim.x;
  const int nwg = gx * gridDim.y;
  const int id = blockIdx.y * gx + blockIdx.x;
  const int chunk = nwg >> 3;
  const int swz = (id & 7) * chunk + (id >> 3);
  int m0 = (swz / gx) * BM;
  int n0 = (swz % gx) * 256;

  const int t = threadIdx.x;
  const int lane = t & 63;
  const int w = t >> 6;

  bool small = false;
  ushort* Cs = nullptr;
  const ushort* Ag;
  const ushort* Bg;
  if constexpr (EPI == EP_UG) {
    if (z == 1) {  // appended 1024^3 weight-product GEMMs (32 blocks)
      if (id >= 32) return;
      const int lid = id & 15;
      m0 = (lid >> 2) * 256;
      n0 = (lid & 3) * 256;
      if (id < 16) { Ag = sA1 + (size_t)m0 * 1024; Bg = sB1 + (size_t)n0 * 1024; Cs = sC1; }
      else         { Ag = sA2 + (size_t)m0 * 1024; Bg = sB2 + (size_t)n0 * 1024; Cs = sC2; }
      small = true;
    }
  }
  if constexpr (EPI == EP_DECAY) {
    if (n0 > m0) return;  // above diagonal: never read by Y (K-clamp)
  }
  if (!small) {
    Ag = A + (size_t)z * sA + (size_t)m0 * lda;
    Bg = Bm + (size_t)z * sB + (size_t)n0 * ldb;
  }

  int Kend = K;
  if constexpr (EPI == EP_YO) Kend = (K < m0 + BM) ? K : m0 + BM;
  const int NT = Kend >> 6;
  const int NTm1 = NT - 1;
  const int NI = NT >> 1;

  // stage-side: lane' pre-applies the st_16x32 swizzle
  const int lp = lane ^ (((lane >> 5) & 1) << 1);
  const int aCol = (lp & 3) * 8;
  const int bRow = (w >> 2) * 64 + (w & 3) * 16 + (lp >> 2);
  int aRow, aRb, aRdBase;
  if constexpr (BM == 256) {
    aRow = (w >> 2) * 128 + (w & 3) * 16 + (lp >> 2);
    aRb = (w >> 2) * 8 + (w & 3);
    aRdBase = (w >> 2) * 8;
  } else {
    aRow = w * 16 + (lp >> 2);
    aRb = w;
    aRdBase = (w >> 2) * 4;
  }
  // read-side
  const int fr = lane & 15;
  const int kg = (lane >> 4) * 8;
  const int cph = kg ^ (((fr >> 3) & 1) << 4);
  const int bRb = ((w & 3) >> 1) * 8 + ((w & 3) & 1) * 4;

  f32x4 acc[MF][4] = {};
  bf16x8 af[4], bfr[2][4];

  if constexpr (BM == 256) {
    STAGE_A(0, 0, 0, 0); STAGE_A(0, 0, 1, 0); STAGE_A(0, 1, 0, 0); STAGE_A(0, 1, 1, 0);
    STAGE_B(0, 0, 0, 0); STAGE_B(0, 0, 1, 0); STAGE_B(0, 1, 0, 0); STAGE_B(0, 1, 1, 0);
    STAGE_B(1, 0, 0, 1); STAGE_B(1, 0, 1, 1); STAGE_B(1, 1, 0, 1); STAGE_B(1, 1, 1, 1);
    STAGE_A(1, 0, 0, 1); STAGE_A(1, 0, 1, 1);
    WAIT_VM(6);
    BAR();
    for (int i = 0; i < NI; ++i) {
      const int tt = 2 * i;
      LOAD_B(0, 0); LOAD_B(0, 1); LOAD_A(0, 0, 0);
      STAGE_A(1, 1, 0, tt + 1); STAGE_A(1, 1, 1, tt + 1);
      WAIT_LGKM8();
      BAR(); WAIT_LGKM0();
      MFMA_PH(0, 0);
      BAR();
      LOAD_A(0, 0, 1);
      STAGE_B(0, 0, 0, tt + 2); STAGE_B(0, 1, 0, tt + 2);
      BAR(); WAIT_LGKM0();
      MFMA_PH(0, 1);
      BAR();
      LOAD_A(0, 1, 0);
      STAGE_B(0, 0, 1, tt + 2); STAGE_B(0, 1, 1, tt + 2);
      BAR(); WAIT_LGKM0();
      MFMA_PH(1, 0);
      BAR();
      LOAD_A(0, 1, 1);
      STAGE_A(0, 0, 0, tt + 2); STAGE_A(0, 0, 1, tt + 2);
      WAIT_VM(6);
      BAR(); WAIT_LGKM0();
      MFMA_PH(1, 1);
      BAR();
      LOAD_B(1, 0); LOAD_B(1, 1); LOAD_A(1, 0, 0);
      STAGE_A(0, 1, 0, tt + 2); STAGE_A(0, 1, 1, tt + 2);
      WAIT_LGKM8();
      BAR(); WAIT_LGKM0();
      MFMA_PH(0, 0);
      BAR();
      LOAD_A(1, 0, 1);
      STAGE_B(1, 0, 0, tt + 3); STAGE_B(1, 1, 0, tt + 3);
      BAR(); WAIT_LGKM0();
      MFMA_PH(0, 1);
      BAR();
      LOAD_A(1, 1, 0);
      STAGE_B(1, 0, 1, tt + 3); STAGE_B(1, 1, 1, tt + 3);
      BAR(); WAIT_LGKM0();
      MFMA_PH(1, 0);
      BAR();
      LOAD_A(1, 1, 1);
      STAGE_A(1, 0, 0, tt + 3); STAGE_A(1, 0, 1, tt + 3);
      WAIT_VM(6);
      BAR(); WAIT_LGKM0();
      MFMA_PH(1, 1);
      BAR();
    }
  } else {
    STAGE_A(0, 0, 0, 0); STAGE_A(0, 0, 1, 0);
    STAGE_B(0, 0, 0, 0); STAGE_B(0, 1, 0, 0); STAGE_B(0, 0, 1, 0); STAGE_B(0, 1, 1, 0);
    STAGE_B(1, 0, 0, 1); STAGE_B(1, 1, 0, 1); STAGE_B(1, 0, 1, 1); STAGE_B(1, 1, 1, 1);
    WAIT_VM(4);
    BAR();
    for (int i = 0; i < NI; ++i) {
      const int tt = 2 * i;
      LOAD_B(0, 0); LOAD_B(0, 1); LOAD_A(0, 0, 0);
      STAGE_A(1, 0, 0, tt + 1); STAGE_A(1, 0, 1, tt + 1);
      WAIT_LGKM8();
      BAR(); WAIT_LGKM0();
      MFMA_PH(0, 0);
      BAR();
      LOAD_A(0, 1, 0);
      STAGE_B(0, 0, 0, tt + 2); STAGE_B(0, 1, 0, tt + 2);
      STAGE_B(0, 0, 1, tt + 2); STAGE_B(0, 1, 1, tt + 2);
      WAIT_VM(4);
      BAR(); WAIT_LGKM0();
      MFMA_PH(1, 0);
      BAR();
      LOAD_B(1, 0); LOAD_B(1, 1); LOAD_A(1, 0, 0);
      STAGE_A(0, 0, 0, tt + 2); STAGE_A(0, 0, 1, tt + 2);
      WAIT_LGKM8();
      BAR(); WAIT_LGKM0();
      MFMA_PH(0, 0);
      BAR();
      LOAD_A(1, 1, 0);
      STAGE_B(1, 0, 0, tt + 3); STAGE_B(1, 1, 0, tt + 3);
      STAGE_B(1, 0, 1, tt + 3); STAGE_B(1, 1, 1, tt + 3);
      WAIT_VM(4);
      BAR(); WAIT_LGKM0();
      MFMA_PH(1, 0);
      BAR();
    }
  }

  // ---- epilogue ---- C/D: col=lane&15, row=(lane>>4)*4+reg
  const int rb4 = (lane >> 4) * 4;
  const int wm = (w >> 2) * (BM / 2), wn = (w & 3) * 64;
  float logd = 0.f;
  if constexpr (EPI == EP_DECAY) logd = __logf(decayp[0]);

#pragma unroll
  for (int mf = 0; mf < MF; ++mf) {
#pragma unroll
    for (int nf = 0; nf < 4; ++nf) {
      const int gm0 = m0 + wm + mf * 16 + rb4;
      const int gn = n0 + wn + nf * 16 + fr;
      if constexpr (EPI == EP_GV) {
        if (gn < 1024) {  // G half: plain bf16
#pragma unroll
          for (int r = 0; r < 4; ++r)
            ((ushort*)O0)[(size_t)(gm0 + r) * 1024 + gn] = f2bf(acc[mf][nf][r]);
        } else {  // v' half: transposed write vT[b][d][t]
          const int d = gn - 1024, b = gm0 >> 11, ttp = gm0 & 2047;
          ushort4 w4;
          w4.x = f2bf(acc[mf][nf][0]); w4.y = f2bf(acc[mf][nf][1]);
          w4.z = f2bf(acc[mf][nf][2]); w4.w = f2bf(acc[mf][nf][3]);
          *(ushort4*)&((ushort*)O1)[(size_t)b * LD + (size_t)d * Ll + ttp] = w4;
        }
      } else {
#pragma unroll
        for (int r = 0; r < 4; ++r) {
          const int gm = gm0 + r;
          const size_t idx = (size_t)z * sC + (size_t)gm * ldc + gn;
          const float v = acc[mf][nf][r];
          if constexpr (EPI == EP_UG) {
            if (small) {
              Cs[(size_t)gm * 1024 + gn] = f2bf(v);
            } else {
              const float b = (gn < 2048) ? bias[gn] : bias2[gn - 2048];
              ((ushort*)O0)[idx] = f2bf(v + b);
            }
          } else if constexpr (EPI == EP_DOWN) {
            ((ushort*)O0)[idx] = f2bf(v + bias[gn]);
          } else if constexpr (EPI == EP_DECAY) {
            ((ushort*)O0)[idx] =
                (gn <= gm) ? f2bf(v * __expf((float)(gm - gn) * logd)) : (ushort)0;
          } else {  // EP_YO: out = x + S@v'
            ((float*)O0)[idx] = v + xres[idx];
          }
        }
      }
    }
  }
}

// One launch for all prep: 4 transposes, 3 straight converts, conv pack,
// rmsnorm.
__global__ __launch_bounds__(256) void prep_k(
    const float* __restrict__ up_w, const float* __restrict__ gate_w,
    const float* __restrict__ down_w, const float* __restrict__ wq,
    const float* __restrict__ wk, const float* __restrict__ wv,
    const float* __restrict__ wo, const float* __restrict__ conv_w,
    const float* __restrict__ x, const float* __restrict__ norm_w,
    ushort* __restrict__ ugw, ushort* __restrict__ down_wT,
    ushort* __restrict__ wq_bf, ushort* __restrict__ wk_bf,
    ushort* __restrict__ wv_bf, ushort* __restrict__ wo_T,
    ushort* __restrict__ cwT, ushort* __restrict__ nrm) {
  const int bid = blockIdx.x;
  const int t = threadIdx.x;
  if (bid < 7168) {  // transposes: fp32 [R][C] -> bf16 [C][R]
    const float* src; ushort* dst; int R, C, idx;
    if (bid < 2048)      { src = up_w;   dst = ugw;               R = 1024; C = 2048; idx = bid; }
    else if (bid < 4096) { src = gate_w; dst = ugw + 2048 * 1024; R = 1024; C = 2048; idx = bid - 2048; }
    else if (bid < 6144) { src = down_w; dst = down_wT;           R = 2048; C = 1024; idx = bid - 4096; }
    else                 { src = wo;     dst = wo_T;              R = 1024; C = 1024; idx = bid - 6144; }
    __shared__ float tile[32][33];
    const int tx = t & 31, ty = t >> 5;
    const int tilesx = C >> 5;
    const int c0 = (idx % tilesx) * 32, r0 = (idx / tilesx) * 32;
#pragma unroll
    for (int i = 0; i < 4; ++i)
      tile[ty + i * 8][tx] = src[(size_t)(r0 + ty + i * 8) * C + c0 + tx];
    __syncthreads();
#pragma unroll
    for (int i = 0; i < 4; ++i)
      dst[(size_t)(c0 + ty + i * 8) * R + r0 + tx] = f2bf(tile[tx][ty + i * 8]);
  } else if (bid < 10240) {  // straight converts wq/wk/wv
    const int seg = (bid - 7168) >> 10;       // 0=wq 1=wk 2=wv
    const int idx = (bid - 7168) & 1023;
    const float* src = (seg == 0) ? wq : (seg == 1) ? wk : wv;
    ushort* dst = (seg == 0) ? wq_bf : (seg == 1) ? wk_bf : wv_bf;
    const size_t e = (size_t)idx * 1024 + t * 4;
    const float4 v = *(const float4*)(src + e);
    ushort4 r;
    r.x = f2bf(v.x); r.y = f2bf(v.y); r.z = f2bf(v.z); r.w = f2bf(v.w);
    *(ushort4*)(dst + e) = r;
  } else if (bid < 10248) {  // conv_w [DI][4] -> cwT [4][DI]
    const int c = (bid - 10240) * 256 + t;
    const float4 v = *(const float4*)(conv_w + c * 4);
    cwT[0 * DIc + c] = f2bf(v.x);
    cwT[1 * DIc + c] = f2bf(v.y);
    cwT[2 * DIc + c] = f2bf(v.z);
    cwT[3 * DIc + c] = f2bf(v.w);
  } else {  // rmsnorm rows
    const int row = bid - 10248;
    const float* xr = x + (size_t)row * Dd;
    const float4 v = *(const float4*)(xr + t * 4);
    float ss = v.x * v.x + v.y * v.y + v.z * v.z + v.w * v.w;
#pragma unroll
    for (int m = 32; m; m >>= 1) ss += __shfl_xor(ss, m);
    __shared__ float red[4];
    if ((t & 63) == 0) red[t >> 6] = ss;
    __syncthreads();
    const float total = red[0] + red[1] + red[2] + red[3];
    const float rs = rsqrtf(total * (1.f / (float)Dd) + 1e-6f);
    const float4 wt = *(const float4*)(norm_w + t * 4);
    ushort4 r;
    r.x = f2bf(v.x * rs * wt.x); r.y = f2bf(v.y * rs * wt.y);
    r.z = f2bf(v.z * rs * wt.z); r.w = f2bf(v.w * rs * wt.w);
    *(ushort4*)(nrm + (size_t)row * Dd + t * 4) = r;
  }
}

// combined = silu(conv(up)+cb) * silu(gate); 8 ch x 8 t per thread
__global__ __launch_bounds__(256) void conv_gate_k(
    const ushort* __restrict__ ug, const ushort* __restrict__ cwT,
    const float* __restrict__ cb, ushort* __restrict__ o) {
  const int t = threadIdx.x;
  const int cg = t & 31;
  const int ts = t >> 5;
  const int cblk = blockIdx.x & 7;
  const int rblk = blockIdx.x >> 3;
  const int c = cblk * 256 + cg * 8;
  const int row0 = rblk * 64 + ts * 8;

  u16x8 w[4];
#pragma unroll
  for (int k = 0; k < 4; ++k) w[k] = *(const u16x8*)&cwT[k * DIc + c];
  float wb[8];
  *(float4*)&wb[0] = *(const float4*)(cb + c);
  *(float4*)&wb[4] = *(const float4*)(cb + c + 4);

  u16x8 h3, h2, h1;
  if ((row0 & (Ll - 1)) == 0) {
    h3 = (u16x8){}; h2 = (u16x8){}; h1 = (u16x8){};
  } else {
    h3 = *(const u16x8*)&ug[(size_t)(row0 - 3) * 4096 + c];
    h2 = *(const u16x8*)&ug[(size_t)(row0 - 2) * 4096 + c];
    h1 = *(const u16x8*)&ug[(size_t)(row0 - 1) * 4096 + c];
  }

#pragma unroll
  for (int i = 0; i < 8; ++i) {
    const size_t rbase = (size_t)(row0 + i) * 4096;
    const u16x8 h0 = *(const u16x8*)&ug[rbase + c];
    const u16x8 g  = *(const u16x8*)&ug[rbase + 2048 + c];
    u16x8 ov;
#pragma unroll
    for (int j = 0; j < 8; ++j) {
      float acc = wb[j];
      acc += bf2f(w[0][j]) * bf2f(h3[j]);
      acc += bf2f(w[1][j]) * bf2f(h2[j]);
      acc += bf2f(w[2][j]) * bf2f(h1[j]);
      acc += bf2f(w[3][j]) * bf2f(h0[j]);
      ov[j] = f2bf(silu(acc) * silu(bf2f(g[j])));
    }
    *(u16x8*)&o[(size_t)(row0 + i) * DIc + c] = ov;
    h3 = h2; h2 = h1; h1 = h0;
  }
}

extern "C" void kernel_launch(void* const* d_in, const int* in_sizes, int n_in,
                              void* d_out, int out_size, void* d_ws,
                              size_t ws_size, hipStream_t stream) {
  const float* x      = (const float*)d_in[0];
  const float* norm_w = (const float*)d_in[1];
  const float* up_w   = (const float*)d_in[2];
  const float* up_b   = (const float*)d_in[3];
  const float* gate_w = (const float*)d_in[4];
  const float* gate_b = (const float*)d_in[5];
  const float* down_w = (const float*)d_in[6];
  const float* down_b = (const float*)d_in[7];
  const float* conv_w = (const float*)d_in[8];
  const float* conv_b = (const float*)d_in[9];
  const float* wq     = (const float*)d_in[10];
  const float* wk     = (const float*)d_in[11];
  const float* wv     = (const float*)d_in[12];
  const float* wo     = (const float*)d_in[13];
  const float* decay  = (const float*)d_in[14];
  float* out = (float*)d_out;
  char* w8 = (char*)d_ws;

  const size_t MiB = 1u << 20;
  ushort* nrm      = (ushort*)(w8 + 0 * MiB);    // 16: normed, later D (down-out)
  ushort* ug       = (ushort*)(w8 + 16 * MiB);   // 64: up|gate [8192][4096]
  ushort* S        = (ushort*)(w8 + 16 * MiB);   // 32 (aliases ug; disjoint life)
  ushort* combined = (ushort*)(w8 + 80 * MiB);   // 32
  ushort* G        = (ushort*)(w8 + 112 * MiB);  // 16: G = D @ W_qk
  ushort* vT       = (ushort*)(w8 + 144 * MiB);  // 16: v'T[b][d][t]
  ushort* ugw      = (ushort*)(w8 + 176 * MiB);  // 8: [4096][1024]
  ushort* down_wT  = (ushort*)(w8 + 184 * MiB);  // 4: [1024][2048]
  ushort* wq_bf    = (ushort*)(w8 + 188 * MiB);  // 2 (raw row-major bf16)
  ushort* wk_bf    = (ushort*)(w8 + 190 * MiB);  // 2
  ushort* wv_bf    = (ushort*)(w8 + 192 * MiB);  // 2
  ushort* wo_T     = (ushort*)(w8 + 194 * MiB);  // 2
  ushort* WsT      = (ushort*)(w8 + 196 * MiB);  // 2: wk @ wq^T
  ushort* Wv2T     = (ushort*)(w8 + 198 * MiB);  // 2: wo^T @ wv^T  (contig w/ WsT)
  ushort* cwT      = (ushort*)(w8 + 200 * MiB);  // 16 KiB

  prep_k<<<18440, 256, 0, stream>>>(up_w, gate_w, down_w, wq, wk, wv, wo,
                                    conv_w, x, norm_w,
                                    ugw, down_wT, wq_bf, wk_bf, wv_bf, wo_T,
                                    cwT, nrm);

  // z=0: ug = normed @ [up_w|gate_w] + biases (512 blocks)
  // z=1: WsT = wk@wq^T, Wv2T = wo^T@wv^T (32 blocks; rest no-op)
  gemm8_k<EP_UG, 256><<<dim3(16, 32, 2), 512, 0, stream>>>(
      nrm, ugw, ug, up_b, gate_b, nullptr, nullptr,
      1024, 1024, 1024, 4096, 0, 0, 0, nullptr,
      wk_bf, wq_bf, WsT, wo_T, wv_bf, Wv2T);

  conv_gate_k<<<1024, 256, 0, stream>>>(ug, cwT, conv_b, combined);

  // D = combined @ down_w + b   (into nrm; normed dead after UG)
  gemm8_k<EP_DOWN, 128><<<dim3(4, 64), 512, 0, stream>>>(
      combined, down_wT, nrm, down_b, nullptr, nullptr, nullptr,
      2048, 2048, 2048, 1024, 0, 0, 0, nullptr,
      nullptr, nullptr, nullptr, nullptr, nullptr, nullptr);

  // [G | v'] = D @ [WsT | Wv2T]^T; v' written transposed into vT
  gemm8_k<EP_GV, 128><<<dim3(8, 64), 512, 0, stream>>>(
      nrm, WsT, G, nullptr, nullptr, nullptr, nullptr,
      1024, 1024, 1024, 1024, 0, 0, 0, vT,
      nullptr, nullptr, nullptr, nullptr, nullptr, nullptr);

  // S = tril(G @ D^T) * d^(t-s)   (lower-triangle blocks only)
  gemm8_k<EP_DECAY, 256><<<dim3(8, 8, Bb), 512, 0, stream>>>(
      G, nrm, S, nullptr, nullptr, nullptr, decay,
      1024, 1024, 1024, 2048, LD, LD, (long)Ll * Ll, nullptr,
      nullptr, nullptr, nullptr, nullptr, nullptr, nullptr);

  // out = x + S @ v'   (K clamped to m0+128 by causality)
  gemm8_k<EP_YO, 128><<<dim3(4, 16, Bb), 512, 0, stream>>>(
      S, vT, out, nullptr, nullptr, x, nullptr,
      2048, 2048, 2048, 1024, (long)Ll * Ll, LD, LD, nullptr,
      nullptr, nullptr, nullptr, nullptr, nullptr, nullptr);
}

// Round 7
// 280.503 us; speedup vs baseline: 4.1779x; 1.1491x over previous
//
#include <hip/hip_runtime.h>

// Fused block, all-bf16 dataflow, 8-phase GEMM template (BN=256, BK=64, 8
// waves, st_16x32 LDS swizzle, counted vmcnt, setprio), BM=256 and BM=128.
// Algebraic folds: S = (D@W_qk)@D^T (W_qk = wq wk^T), wo folded into v:
// v' = D@(wv wo), out = x + S@v'. The two 1024^3 weight-product GEMMs run as
// 128 leading 256-thread blocks inside the conv_gate dispatch (backfilled by
// the memory-bound conv blocks; avoids a 1-block/CU tail round on UG).

typedef __bf16 bf16x8 __attribute__((ext_vector_type(8)));
typedef unsigned short u16x8 __attribute__((ext_vector_type(8)));
typedef float f32x4 __attribute__((ext_vector_type(4)));

constexpr int Bb = 4, Ll = 2048, Dd = 1024, DIc = 2048;
constexpr long LD  = (long)Ll * Dd;   // 2,097,152
constexpr long BLD = (long)Bb * LD;   // 8,388,608

static __device__ __forceinline__ unsigned short f2bf(float f) {
  unsigned u = __builtin_bit_cast(unsigned, f);
  u += 0x7fffu + ((u >> 16) & 1u);  // RNE
  return (unsigned short)(u >> 16);
}
static __device__ __forceinline__ float bf2f(unsigned short u) {
  return __builtin_bit_cast(float, (unsigned)u << 16);
}
static __device__ __forceinline__ float silu(float g) {
  return g / (1.f + __expf(-g));
}

enum { EP_UG = 0, EP_DOWN, EP_GV, EP_DECAY, EP_YO };

#define STAGE_A(DBUF, MG, KH, TILE) {                                          \
    const int kt_ = ((TILE) < NTm1 ? (TILE) : NTm1);                           \
    __builtin_amdgcn_global_load_lds(                                          \
      (const __attribute__((address_space(1))) void*)                          \
        (Ag + (size_t)(aRow + (MG)*64) * lda + kt_*64 + (KH)*32 + aCol),       \
      (__attribute__((address_space(3))) void*)                                \
        (lds + (DBUF)*ADB + (KH)*AKH + (aRb + (MG)*4)*512), 16, 0, 0); }

#define STAGE_B(DBUF, NH, KH, TILE) {                                          \
    const int kt_ = ((TILE) < NTm1 ? (TILE) : NTm1);                           \
    __builtin_amdgcn_global_load_lds(                                          \
      (const __attribute__((address_space(1))) void*)                          \
        (Bg + (size_t)(bRow + (NH)*128) * ldb + kt_*64 + (KH)*32 + aCol),      \
      (__attribute__((address_space(3))) void*)                                \
        (lds + BOFF + (DBUF)*16384 + (KH)*8192 + ((NH)*8 + w)*512), 16, 0, 0); }

#define LOAD_A(DBUF, KS, MG) {                                                 \
  _Pragma("unroll") for (int j_ = 0; j_ < 4; ++j_)                             \
    af[j_] = *(const bf16x8*)&lds[(DBUF)*ADB + (KS)*AKH +                      \
        (aRdBase + (MG)*4 + j_)*512 + fr*32 + cph]; }

#define LOAD_B(DBUF, KS) {                                                     \
  _Pragma("unroll") for (int n_ = 0; n_ < 4; ++n_)                             \
    bfr[KS][n_] = *(const bf16x8*)&lds[BOFF + (DBUF)*16384 + (KS)*8192 +       \
        (bRb + n_)*512 + fr*32 + cph]; }

#define MFMA_PH(KS, MG) {                                                      \
  __builtin_amdgcn_s_setprio(1);                                               \
  _Pragma("unroll") for (int j_ = 0; j_ < 4; ++j_)                             \
  _Pragma("unroll") for (int n_ = 0; n_ < 4; ++n_)                             \
    acc[(MG)*4 + j_][n_] = __builtin_amdgcn_mfma_f32_16x16x32_bf16(            \
        af[j_], bfr[KS][n_], acc[(MG)*4 + j_][n_], 0, 0, 0);                   \
  __builtin_amdgcn_s_setprio(0); }

#define BAR() __builtin_amdgcn_s_barrier()
#define WAIT_LGKM0() { asm volatile("s_waitcnt lgkmcnt(0)" ::: "memory");      \
                       __builtin_amdgcn_sched_barrier(0); }
#define WAIT_LGKM8() asm volatile("s_waitcnt lgkmcnt(8)" ::: "memory")
#define WAIT_VM(N) asm volatile("s_waitcnt vmcnt(" #N ")" ::: "memory")

template <int EPI, int BM>
__global__ __launch_bounds__(512, 2) void gemm8_k(
    const ushort* __restrict__ A, const ushort* __restrict__ Bm,
    void* __restrict__ O0, const float* __restrict__ bias,
    const float* __restrict__ bias2, const float* __restrict__ xres,
    const float* __restrict__ decayp,
    int K, int lda, int ldb, int ldc,
    long sA, long sB, long sC,
    void* __restrict__ O1) {
  constexpr int MF = BM / 32;
  constexpr int ADB = BM * 64;
  constexpr int AKH = BM * 32;
  constexpr int BOFF = BM * 128;
  __shared__ ushort lds[BM == 256 ? 65536 : 49152];

  const int z = blockIdx.z;
  const int gx = gridDim.x;
  const int nwg = gx * gridDim.y;
  const int id = blockIdx.y * gx + blockIdx.x;
  const int chunk = nwg >> 3;
  const int swz = (id & 7) * chunk + (id >> 3);
  const int m0 = (swz / gx) * BM;
  const int n0 = (swz % gx) * 256;

  const int t = threadIdx.x;
  const int lane = t & 63;
  const int w = t >> 6;

  if constexpr (EPI == EP_DECAY) {
    if (n0 > m0) return;  // above diagonal: never read by YO (K-clamp)
  }
  const ushort* Ag = A + (size_t)z * sA + (size_t)m0 * lda;
  const ushort* Bg = Bm + (size_t)z * sB + (size_t)n0 * ldb;

  int Kend = K;
  if constexpr (EPI == EP_YO) Kend = (K < m0 + BM) ? K : m0 + BM;
  const int NT = Kend >> 6;
  const int NTm1 = NT - 1;
  const int NI = NT >> 1;

  // stage-side: lane' pre-applies the st_16x32 swizzle
  const int lp = lane ^ (((lane >> 5) & 1) << 1);
  const int aCol = (lp & 3) * 8;
  const int bRow = (w >> 2) * 64 + (w & 3) * 16 + (lp >> 2);
  int aRow, aRb, aRdBase;
  if constexpr (BM == 256) {
    aRow = (w >> 2) * 128 + (w & 3) * 16 + (lp >> 2);
    aRb = (w >> 2) * 8 + (w & 3);
    aRdBase = (w >> 2) * 8;
  } else {
    aRow = w * 16 + (lp >> 2);
    aRb = w;
    aRdBase = (w >> 2) * 4;
  }
  // read-side
  const int fr = lane & 15;
  const int kg = (lane >> 4) * 8;
  const int cph = kg ^ (((fr >> 3) & 1) << 4);
  const int bRb = ((w & 3) >> 1) * 8 + ((w & 3) & 1) * 4;

  f32x4 acc[MF][4] = {};
  bf16x8 af[4], bfr[2][4];

  if constexpr (BM == 256) {
    STAGE_A(0, 0, 0, 0); STAGE_A(0, 0, 1, 0); STAGE_A(0, 1, 0, 0); STAGE_A(0, 1, 1, 0);
    STAGE_B(0, 0, 0, 0); STAGE_B(0, 0, 1, 0); STAGE_B(0, 1, 0, 0); STAGE_B(0, 1, 1, 0);
    STAGE_B(1, 0, 0, 1); STAGE_B(1, 0, 1, 1); STAGE_B(1, 1, 0, 1); STAGE_B(1, 1, 1, 1);
    STAGE_A(1, 0, 0, 1); STAGE_A(1, 0, 1, 1);
    WAIT_VM(6);
    BAR();
    for (int i = 0; i < NI; ++i) {
      const int tt = 2 * i;
      LOAD_B(0, 0); LOAD_B(0, 1); LOAD_A(0, 0, 0);
      STAGE_A(1, 1, 0, tt + 1); STAGE_A(1, 1, 1, tt + 1);
      WAIT_LGKM8();
      BAR(); WAIT_LGKM0();
      MFMA_PH(0, 0);
      BAR();
      LOAD_A(0, 0, 1);
      STAGE_B(0, 0, 0, tt + 2); STAGE_B(0, 1, 0, tt + 2);
      BAR(); WAIT_LGKM0();
      MFMA_PH(0, 1);
      BAR();
      LOAD_A(0, 1, 0);
      STAGE_B(0, 0, 1, tt + 2); STAGE_B(0, 1, 1, tt + 2);
      BAR(); WAIT_LGKM0();
      MFMA_PH(1, 0);
      BAR();
      LOAD_A(0, 1, 1);
      STAGE_A(0, 0, 0, tt + 2); STAGE_A(0, 0, 1, tt + 2);
      WAIT_VM(6);
      BAR(); WAIT_LGKM0();
      MFMA_PH(1, 1);
      BAR();
      LOAD_B(1, 0); LOAD_B(1, 1); LOAD_A(1, 0, 0);
      STAGE_A(0, 1, 0, tt + 2); STAGE_A(0, 1, 1, tt + 2);
      WAIT_LGKM8();
      BAR(); WAIT_LGKM0();
      MFMA_PH(0, 0);
      BAR();
      LOAD_A(1, 0, 1);
      STAGE_B(1, 0, 0, tt + 3); STAGE_B(1, 1, 0, tt + 3);
      BAR(); WAIT_LGKM0();
      MFMA_PH(0, 1);
      BAR();
      LOAD_A(1, 1, 0);
      STAGE_B(1, 0, 1, tt + 3); STAGE_B(1, 1, 1, tt + 3);
      BAR(); WAIT_LGKM0();
      MFMA_PH(1, 0);
      BAR();
      LOAD_A(1, 1, 1);
      STAGE_A(1, 0, 0, tt + 3); STAGE_A(1, 0, 1, tt + 3);
      WAIT_VM(6);
      BAR(); WAIT_LGKM0();
      MFMA_PH(1, 1);
      BAR();
    }
  } else {
    STAGE_A(0, 0, 0, 0); STAGE_A(0, 0, 1, 0);
    STAGE_B(0, 0, 0, 0); STAGE_B(0, 1, 0, 0); STAGE_B(0, 0, 1, 0); STAGE_B(0, 1, 1, 0);
    STAGE_B(1, 0, 0, 1); STAGE_B(1, 1, 0, 1); STAGE_B(1, 0, 1, 1); STAGE_B(1, 1, 1, 1);
    WAIT_VM(4);
    BAR();
    for (int i = 0; i < NI; ++i) {
      const int tt = 2 * i;
      LOAD_B(0, 0); LOAD_B(0, 1); LOAD_A(0, 0, 0);
      STAGE_A(1, 0, 0, tt + 1); STAGE_A(1, 0, 1, tt + 1);
      WAIT_LGKM8();
      BAR(); WAIT_LGKM0();
      MFMA_PH(0, 0);
      BAR();
      LOAD_A(0, 1, 0);
      STAGE_B(0, 0, 0, tt + 2); STAGE_B(0, 1, 0, tt + 2);
      STAGE_B(0, 0, 1, tt + 2); STAGE_B(0, 1, 1, tt + 2);
      WAIT_VM(4);
      BAR(); WAIT_LGKM0();
      MFMA_PH(1, 0);
      BAR();
      LOAD_B(1, 0); LOAD_B(1, 1); LOAD_A(1, 0, 0);
      STAGE_A(0, 0, 0, tt + 2); STAGE_A(0, 0, 1, tt + 2);
      WAIT_LGKM8();
      BAR(); WAIT_LGKM0();
      MFMA_PH(0, 0);
      BAR();
      LOAD_A(1, 1, 0);
      STAGE_B(1, 0, 0, tt + 3); STAGE_B(1, 1, 0, tt + 3);
      STAGE_B(1, 0, 1, tt + 3); STAGE_B(1, 1, 1, tt + 3);
      WAIT_VM(4);
      BAR(); WAIT_LGKM0();
      MFMA_PH(1, 0);
      BAR();
    }
  }

  // ---- epilogue ---- C/D: col=lane&15, row=(lane>>4)*4+reg
  const int rb4 = (lane >> 4) * 4;
  const int wm = (w >> 2) * (BM / 2), wn = (w & 3) * 64;
  float logd = 0.f;
  if constexpr (EPI == EP_DECAY) logd = __logf(decayp[0]);

#pragma unroll
  for (int mf = 0; mf < MF; ++mf) {
#pragma unroll
    for (int nf = 0; nf < 4; ++nf) {
      const int gm0 = m0 + wm + mf * 16 + rb4;
      const int gn = n0 + wn + nf * 16 + fr;
      if constexpr (EPI == EP_GV) {
        if (gn < 1024) {  // G half: plain bf16
#pragma unroll
          for (int r = 0; r < 4; ++r)
            ((ushort*)O0)[(size_t)(gm0 + r) * 1024 + gn] = f2bf(acc[mf][nf][r]);
        } else {  // v' half: transposed write vT[b][d][t]
          const int d = gn - 1024, b = gm0 >> 11, ttp = gm0 & 2047;
          ushort4 w4;
          w4.x = f2bf(acc[mf][nf][0]); w4.y = f2bf(acc[mf][nf][1]);
          w4.z = f2bf(acc[mf][nf][2]); w4.w = f2bf(acc[mf][nf][3]);
          *(ushort4*)&((ushort*)O1)[(size_t)b * LD + (size_t)d * Ll + ttp] = w4;
        }
      } else {
#pragma unroll
        for (int r = 0; r < 4; ++r) {
          const int gm = gm0 + r;
          const size_t idx = (size_t)z * sC + (size_t)gm * ldc + gn;
          const float v = acc[mf][nf][r];
          if constexpr (EPI == EP_UG) {
            const float b = (gn < 2048) ? bias[gn] : bias2[gn - 2048];
            ((ushort*)O0)[idx] = f2bf(v + b);
          } else if constexpr (EPI == EP_DOWN) {
            ((ushort*)O0)[idx] = f2bf(v + bias[gn]);
          } else if constexpr (EPI == EP_DECAY) {
            ((ushort*)O0)[idx] =
                (gn <= gm) ? f2bf(v * __expf((float)(gm - gn) * logd)) : (ushort)0;
          } else {  // EP_YO: out = x + S@v'
            ((float*)O0)[idx] = v + xres[idx];
          }
        }
      }
    }
  }
}

// One launch for all prep: 4 transposes, 3 straight converts, conv pack,
// rmsnorm.
__global__ __launch_bounds__(256) void prep_k(
    const float* __restrict__ up_w, const float* __restrict__ gate_w,
    const float* __restrict__ down_w, const float* __restrict__ wq,
    const float* __restrict__ wk, const float* __restrict__ wv,
    const float* __restrict__ wo, const float* __restrict__ conv_w,
    const float* __restrict__ x, const float* __restrict__ norm_w,
    ushort* __restrict__ ugw, ushort* __restrict__ down_wT,
    ushort* __restrict__ wq_bf, ushort* __restrict__ wk_bf,
    ushort* __restrict__ wv_bf, ushort* __restrict__ wo_T,
    ushort* __restrict__ cwT, ushort* __restrict__ nrm) {
  const int bid = blockIdx.x;
  const int t = threadIdx.x;
  if (bid < 7168) {  // transposes: fp32 [R][C] -> bf16 [C][R]
    const float* src; ushort* dst; int R, C, idx;
    if (bid < 2048)      { src = up_w;   dst = ugw;               R = 1024; C = 2048; idx = bid; }
    else if (bid < 4096) { src = gate_w; dst = ugw + 2048 * 1024; R = 1024; C = 2048; idx = bid - 2048; }
    else if (bid < 6144) { src = down_w; dst = down_wT;           R = 2048; C = 1024; idx = bid - 4096; }
    else                 { src = wo;     dst = wo_T;              R = 1024; C = 1024; idx = bid - 6144; }
    __shared__ float tile[32][33];
    const int tx = t & 31, ty = t >> 5;
    const int tilesx = C >> 5;
    const int c0 = (idx % tilesx) * 32, r0 = (idx / tilesx) * 32;
#pragma unroll
    for (int i = 0; i < 4; ++i)
      tile[ty + i * 8][tx] = src[(size_t)(r0 + ty + i * 8) * C + c0 + tx];
    __syncthreads();
#pragma unroll
    for (int i = 0; i < 4; ++i)
      dst[(size_t)(c0 + ty + i * 8) * R + r0 + tx] = f2bf(tile[tx][ty + i * 8]);
  } else if (bid < 10240) {  // straight converts wq/wk/wv
    const int seg = (bid - 7168) >> 10;       // 0=wq 1=wk 2=wv
    const int idx = (bid - 7168) & 1023;
    const float* src = (seg == 0) ? wq : (seg == 1) ? wk : wv;
    ushort* dst = (seg == 0) ? wq_bf : (seg == 1) ? wk_bf : wv_bf;
    const size_t e = (size_t)idx * 1024 + t * 4;
    const float4 v = *(const float4*)(src + e);
    ushort4 r;
    r.x = f2bf(v.x); r.y = f2bf(v.y); r.z = f2bf(v.z); r.w = f2bf(v.w);
    *(ushort4*)(dst + e) = r;
  } else if (bid < 10248) {  // conv_w [DI][4] -> cwT [4][DI]
    const int c = (bid - 10240) * 256 + t;
    const float4 v = *(const float4*)(conv_w + c * 4);
    cwT[0 * DIc + c] = f2bf(v.x);
    cwT[1 * DIc + c] = f2bf(v.y);
    cwT[2 * DIc + c] = f2bf(v.z);
    cwT[3 * DIc + c] = f2bf(v.w);
  } else {  // rmsnorm rows
    const int row = bid - 10248;
    const float* xr = x + (size_t)row * Dd;
    const float4 v = *(const float4*)(xr + t * 4);
    float ss = v.x * v.x + v.y * v.y + v.z * v.z + v.w * v.w;
#pragma unroll
    for (int m = 32; m; m >>= 1) ss += __shfl_xor(ss, m);
    __shared__ float red[4];
    if ((t & 63) == 0) red[t >> 6] = ss;
    __syncthreads();
    const float total = red[0] + red[1] + red[2] + red[3];
    const float rs = rsqrtf(total * (1.f / (float)Dd) + 1e-6f);
    const float4 wt = *(const float4*)(norm_w + t * 4);
    ushort4 r;
    r.x = f2bf(v.x * rs * wt.x); r.y = f2bf(v.y * rs * wt.y);
    r.z = f2bf(v.z * rs * wt.z); r.w = f2bf(v.w * rs * wt.w);
    *(ushort4*)(nrm + (size_t)row * Dd + t * 4) = r;
  }
}

// bid<128: 256-thread m97-style 128x128 weight-product GEMM blocks
//   (WsT = wk@wq^T, Wv2T = wo^T@wv^T; inputs prepped by prep_k).
// bid>=128: conv: combined = silu(conv(up)+cb)*silu(gate), 8ch x 8t/thread.
__global__ __launch_bounds__(256) void conv_gate_k(
    const ushort* __restrict__ ug, const ushort* __restrict__ cwT,
    const float* __restrict__ cb, ushort* __restrict__ o,
    const ushort* __restrict__ wk_bf, const ushort* __restrict__ wq_bf,
    const ushort* __restrict__ wo_T, const ushort* __restrict__ wv_bf,
    ushort* __restrict__ WsT, ushort* __restrict__ Wv2T) {
  const int bid = blockIdx.x;
  const int t = threadIdx.x;
  if (bid < 128) {
    __shared__ ushort lds[8192];
    ushort* As = lds;
    ushort* Bs = lds + 4096;
    const int oo = bid >> 6, lid = bid & 63;
    const int m0 = (lid >> 3) * 128, n0 = (lid & 7) * 128;
    const ushort* A = (oo ? wo_T : wk_bf) + (size_t)m0 * 1024;
    const ushort* B = (oo ? wv_bf : wq_bf) + (size_t)n0 * 1024;
    ushort* C = oo ? Wv2T : WsT;
    const int lane = t & 63, wave = t >> 6;
    const int wm = (wave >> 1) * 64, wn = (wave & 1) * 64;
    const int fr = lane & 15, kg = (lane >> 4) * 8;
    const int srow0 = wave * 16 + (lane >> 2), scol = (lane & 3) * 8;
    f32x4 acc[4][4] = {};
    for (int k0 = 0; k0 < 1024; k0 += 32) {
#pragma unroll
      for (int p = 0; p < 2; ++p) {
        __builtin_amdgcn_global_load_lds(
            (const __attribute__((address_space(1))) void*)
                (A + (size_t)(srow0 + p * 64) * 1024 + k0 + scol),
            (__attribute__((address_space(3))) void*)(As + (p * 4 + wave) * 512),
            16, 0, 0);
        __builtin_amdgcn_global_load_lds(
            (const __attribute__((address_space(1))) void*)
                (B + (size_t)(srow0 + p * 64) * 1024 + k0 + scol),
            (__attribute__((address_space(3))) void*)(Bs + (p * 4 + wave) * 512),
            16, 0, 0);
      }
      __syncthreads();
      bf16x8 af[4], bv[4];
#pragma unroll
      for (int i = 0; i < 4; ++i) {
        af[i] = *(const bf16x8*)&As[(wm + i * 16 + fr) * 32 + kg];
        bv[i] = *(const bf16x8*)&Bs[(wn + i * 16 + fr) * 32 + kg];
      }
#pragma unroll
      for (int mi = 0; mi < 4; ++mi)
#pragma unroll
        for (int ni = 0; ni < 4; ++ni)
          acc[mi][ni] = __builtin_amdgcn_mfma_f32_16x16x32_bf16(
              af[mi], bv[ni], acc[mi][ni], 0, 0, 0);
      __syncthreads();
    }
    const int rb = (lane >> 4) * 4;
#pragma unroll
    for (int mi = 0; mi < 4; ++mi)
#pragma unroll
      for (int ni = 0; ni < 4; ++ni)
#pragma unroll
        for (int r = 0; r < 4; ++r)
          C[(size_t)(m0 + wm + mi * 16 + rb + r) * 1024 + n0 + wn + ni * 16 + fr] =
              f2bf(acc[mi][ni][r]);
    return;
  }

  const int cbid = bid - 128;
  const int cg = t & 31;
  const int ts = t >> 5;
  const int cblk = cbid & 7;
  const int rblk = cbid >> 3;
  const int c = cblk * 256 + cg * 8;
  const int row0 = rblk * 64 + ts * 8;

  u16x8 w[4];
#pragma unroll
  for (int k = 0; k < 4; ++k) w[k] = *(const u16x8*)&cwT[k * DIc + c];
  float wb[8];
  *(float4*)&wb[0] = *(const float4*)(cb + c);
  *(float4*)&wb[4] = *(const float4*)(cb + c + 4);

  u16x8 h3, h2, h1;
  if ((row0 & (Ll - 1)) == 0) {
    h3 = (u16x8){}; h2 = (u16x8){}; h1 = (u16x8){};
  } else {
    h3 = *(const u16x8*)&ug[(size_t)(row0 - 3) * 4096 + c];
    h2 = *(const u16x8*)&ug[(size_t)(row0 - 2) * 4096 + c];
    h1 = *(const u16x8*)&ug[(size_t)(row0 - 1) * 4096 + c];
  }

#pragma unroll
  for (int i = 0; i < 8; ++i) {
    const size_t rbase = (size_t)(row0 + i) * 4096;
    const u16x8 h0 = *(const u16x8*)&ug[rbase + c];
    const u16x8 g  = *(const u16x8*)&ug[rbase + 2048 + c];
    u16x8 ov;
#pragma unroll
    for (int j = 0; j < 8; ++j) {
      float acc = wb[j];
      acc += bf2f(w[0][j]) * bf2f(h3[j]);
      acc += bf2f(w[1][j]) * bf2f(h2[j]);
      acc += bf2f(w[2][j]) * bf2f(h1[j]);
      acc += bf2f(w[3][j]) * bf2f(h0[j]);
      ov[j] = f2bf(silu(acc) * silu(bf2f(g[j])));
    }
    *(u16x8*)&o[(size_t)(row0 + i) * DIc + c] = ov;
    h3 = h2; h2 = h1; h1 = h0;
  }
}

extern "C" void kernel_launch(void* const* d_in, const int* in_sizes, int n_in,
                              void* d_out, int out_size, void* d_ws,
                              size_t ws_size, hipStream_t stream) {
  const float* x      = (const float*)d_in[0];
  const float* norm_w = (const float*)d_in[1];
  const float* up_w   = (const float*)d_in[2];
  const float* up_b   = (const float*)d_in[3];
  const float* gate_w = (const float*)d_in[4];
  const float* gate_b = (const float*)d_in[5];
  const float* down_w = (const float*)d_in[6];
  const float* down_b = (const float*)d_in[7];
  const float* conv_w = (const float*)d_in[8];
  const float* conv_b = (const float*)d_in[9];
  const float* wq     = (const float*)d_in[10];
  const float* wk     = (const float*)d_in[11];
  const float* wv     = (const float*)d_in[12];
  const float* wo     = (const float*)d_in[13];
  const float* decay  = (const float*)d_in[14];
  float* out = (float*)d_out;
  char* w8 = (char*)d_ws;

  const size_t MiB = 1u << 20;
  ushort* nrm      = (ushort*)(w8 + 0 * MiB);    // 16: normed, later D (down-out)
  ushort* ug       = (ushort*)(w8 + 16 * MiB);   // 64: up|gate [8192][4096]
  ushort* S        = (ushort*)(w8 + 16 * MiB);   // 32 (aliases ug; disjoint life)
  ushort* combined = (ushort*)(w8 + 80 * MiB);   // 32
  ushort* G        = (ushort*)(w8 + 112 * MiB);  // 16: G = D @ W_qk
  ushort* vT       = (ushort*)(w8 + 144 * MiB);  // 16: v'T[b][d][t]
  ushort* ugw      = (ushort*)(w8 + 176 * MiB);  // 8: [4096][1024]
  ushort* down_wT  = (ushort*)(w8 + 184 * MiB);  // 4: [1024][2048]
  ushort* wq_bf    = (ushort*)(w8 + 188 * MiB);  // 2 (raw row-major bf16)
  ushort* wk_bf    = (ushort*)(w8 + 190 * MiB);  // 2
  ushort* wv_bf    = (ushort*)(w8 + 192 * MiB);  // 2
  ushort* wo_T     = (ushort*)(w8 + 194 * MiB);  // 2
  ushort* WsT      = (ushort*)(w8 + 196 * MiB);  // 2: wk @ wq^T
  ushort* Wv2T     = (ushort*)(w8 + 198 * MiB);  // 2: wo^T @ wv^T (contig w/ WsT)
  ushort* cwT      = (ushort*)(w8 + 200 * MiB);  // 16 KiB

  prep_k<<<18440, 256, 0, stream>>>(up_w, gate_w, down_w, wq, wk, wv, wo,
                                    conv_w, x, norm_w,
                                    ugw, down_wT, wq_bf, wk_bf, wv_bf, wo_T,
                                    cwT, nrm);

  // ug = normed @ [up_w|gate_w] + biases  (512 blocks = 2.0 waves)
  gemm8_k<EP_UG, 256><<<dim3(16, 32), 512, 0, stream>>>(
      nrm, ugw, ug, up_b, gate_b, nullptr, nullptr,
      1024, 1024, 1024, 4096, 0, 0, 0, nullptr);

  // 128 weight-product GEMM blocks (first) + 1024 conv blocks (backfill)
  conv_gate_k<<<1152, 256, 0, stream>>>(ug, cwT, conv_b, combined,
                                        wk_bf, wq_bf, wo_T, wv_bf, WsT, Wv2T);

  // D = combined @ down_w + b   (into nrm; normed dead after UG)
  gemm8_k<EP_DOWN, 128><<<dim3(4, 64), 512, 0, stream>>>(
      combined, down_wT, nrm, down_b, nullptr, nullptr, nullptr,
      2048, 2048, 2048, 1024, 0, 0, 0, nullptr);

  // [G | v'] = D @ [WsT | Wv2T]^T; v' written transposed into vT
  gemm8_k<EP_GV, 128><<<dim3(8, 64), 512, 0, stream>>>(
      nrm, WsT, G, nullptr, nullptr, nullptr, nullptr,
      1024, 1024, 1024, 1024, 0, 0, 0, vT);

  // S = tril(G @ D^T) * d^(t-s)   (lower-triangle blocks only)
  gemm8_k<EP_DECAY, 256><<<dim3(8, 8, Bb), 512, 0, stream>>>(
      G, nrm, S, nullptr, nullptr, nullptr, decay,
      1024, 1024, 1024, 2048, LD, LD, (long)Ll * Ll, nullptr);

  // out = x + S @ v'   (K clamped to m0+128 by causality)
  gemm8_k<EP_YO, 128><<<dim3(4, 16, Bb), 512, 0, stream>>>(
      S, vT, out, nullptr, nullptr, x, nullptr,
      2048, 2048, 2048, 1024, (long)Ll * Ll, LD, LD, nullptr);
}

// Round 8
// 273.656 us; speedup vs baseline: 4.2824x; 1.0250x over previous
//
#include <hip/hip_runtime.h>

// Fused block, all-bf16 dataflow. GEMMs: 8-phase 512-thread template
// (BM=256/128, BN=256, BK=64, st_16x32 LDS swizzle, counted vmcnt, setprio)
// plus a 256-thread 4-wave BM=128/BN=128 variant (64 KiB LDS, 2 blocks/CU)
// for the load-imbalanced attention GEMMs (DECAY tril, YO causal-K).
// Algebraic folds: S = (D@W_qk)@D^T (W_qk = wq wk^T), wo folded into v.

typedef __bf16 bf16x8 __attribute__((ext_vector_type(8)));
typedef unsigned short u16x8 __attribute__((ext_vector_type(8)));
typedef float f32x4 __attribute__((ext_vector_type(4)));

constexpr int Bb = 4, Ll = 2048, Dd = 1024, DIc = 2048;
constexpr long LD  = (long)Ll * Dd;   // 2,097,152
constexpr long BLD = (long)Bb * LD;   // 8,388,608

static __device__ __forceinline__ unsigned short f2bf(float f) {
  unsigned u = __builtin_bit_cast(unsigned, f);
  u += 0x7fffu + ((u >> 16) & 1u);  // RNE
  return (unsigned short)(u >> 16);
}
static __device__ __forceinline__ float bf2f(unsigned short u) {
  return __builtin_bit_cast(float, (unsigned)u << 16);
}
static __device__ __forceinline__ float silu(float g) {
  return g / (1.f + __expf(-g));
}

enum { EP_UG = 0, EP_DOWN, EP_GV, EP_DECAY, EP_YO };

#define STAGE_A(DBUF, MG, KH, TILE) {                                          \
    const int kt_ = ((TILE) < NTm1 ? (TILE) : NTm1);                           \
    __builtin_amdgcn_global_load_lds(                                          \
      (const __attribute__((address_space(1))) void*)                          \
        (Ag + (size_t)(aRow + (MG)*64) * lda + kt_*64 + (KH)*32 + aCol),       \
      (__attribute__((address_space(3))) void*)                                \
        (lds + (DBUF)*ADB + (KH)*AKH + (aRb + (MG)*4)*512), 16, 0, 0); }

#define STAGE_B(DBUF, NH, KH, TILE) {                                          \
    const int kt_ = ((TILE) < NTm1 ? (TILE) : NTm1);                           \
    __builtin_amdgcn_global_load_lds(                                          \
      (const __attribute__((address_space(1))) void*)                          \
        (Bg + (size_t)(bRow + (NH)*128) * ldb + kt_*64 + (KH)*32 + aCol),      \
      (__attribute__((address_space(3))) void*)                                \
        (lds + BOFF + (DBUF)*16384 + (KH)*8192 + ((NH)*8 + w)*512), 16, 0, 0); }

#define LOAD_A(DBUF, KS, MG) {                                                 \
  _Pragma("unroll") for (int j_ = 0; j_ < 4; ++j_)                             \
    af[j_] = *(const bf16x8*)&lds[(DBUF)*ADB + (KS)*AKH +                      \
        (aRdBase + (MG)*4 + j_)*512 + fr*32 + cph]; }

#define LOAD_B(DBUF, KS) {                                                     \
  _Pragma("unroll") for (int n_ = 0; n_ < 4; ++n_)                             \
    bfr[KS][n_] = *(const bf16x8*)&lds[BOFF + (DBUF)*16384 + (KS)*8192 +       \
        (bRb + n_)*512 + fr*32 + cph]; }

#define MFMA_PH(KS, MG) {                                                      \
  __builtin_amdgcn_s_setprio(1);                                               \
  _Pragma("unroll") for (int j_ = 0; j_ < 4; ++j_)                             \
  _Pragma("unroll") for (int n_ = 0; n_ < 4; ++n_)                             \
    acc[(MG)*4 + j_][n_] = __builtin_amdgcn_mfma_f32_16x16x32_bf16(            \
        af[j_], bfr[KS][n_], acc[(MG)*4 + j_][n_], 0, 0, 0);                   \
  __builtin_amdgcn_s_setprio(0); }

#define BAR() __builtin_amdgcn_s_barrier()
#define WAIT_LGKM0() { asm volatile("s_waitcnt lgkmcnt(0)" ::: "memory");      \
                       __builtin_amdgcn_sched_barrier(0); }
#define WAIT_LGKM8() asm volatile("s_waitcnt lgkmcnt(8)" ::: "memory")
#define WAIT_VM(N) asm volatile("s_waitcnt vmcnt(" #N ")" ::: "memory")

template <int EPI, int BM>
__global__ __launch_bounds__(512, 2) void gemm8_k(
    const ushort* __restrict__ A, const ushort* __restrict__ Bm,
    void* __restrict__ O0, const float* __restrict__ bias,
    const float* __restrict__ bias2,
    int K, int lda, int ldb, int ldc,
    long sA, long sB, long sC,
    void* __restrict__ O1) {
  constexpr int MF = BM / 32;
  constexpr int ADB = BM * 64;
  constexpr int AKH = BM * 32;
  constexpr int BOFF = BM * 128;
  __shared__ ushort lds[BM == 256 ? 65536 : 49152];

  const int z = blockIdx.z;
  const int gx = gridDim.x;
  const int nwg = gx * gridDim.y;
  const int id = blockIdx.y * gx + blockIdx.x;
  const int chunk = nwg >> 3;
  const int swz = (id & 7) * chunk + (id >> 3);
  const int m0 = (swz / gx) * BM;
  const int n0 = (swz % gx) * 256;

  const int t = threadIdx.x;
  const int lane = t & 63;
  const int w = t >> 6;

  const ushort* Ag = A + (size_t)z * sA + (size_t)m0 * lda;
  const ushort* Bg = Bm + (size_t)z * sB + (size_t)n0 * ldb;

  const int NT = K >> 6;
  const int NTm1 = NT - 1;
  const int NI = NT >> 1;

  // stage-side: lane' pre-applies the st_16x32 swizzle
  const int lp = lane ^ (((lane >> 5) & 1) << 1);
  const int aCol = (lp & 3) * 8;
  const int bRow = (w >> 2) * 64 + (w & 3) * 16 + (lp >> 2);
  int aRow, aRb, aRdBase;
  if constexpr (BM == 256) {
    aRow = (w >> 2) * 128 + (w & 3) * 16 + (lp >> 2);
    aRb = (w >> 2) * 8 + (w & 3);
    aRdBase = (w >> 2) * 8;
  } else {
    aRow = w * 16 + (lp >> 2);
    aRb = w;
    aRdBase = (w >> 2) * 4;
  }
  // read-side
  const int fr = lane & 15;
  const int kg = (lane >> 4) * 8;
  const int cph = kg ^ (((fr >> 3) & 1) << 4);
  const int bRb = ((w & 3) >> 1) * 8 + ((w & 3) & 1) * 4;

  f32x4 acc[MF][4] = {};
  bf16x8 af[4], bfr[2][4];

  if constexpr (BM == 256) {
    STAGE_A(0, 0, 0, 0); STAGE_A(0, 0, 1, 0); STAGE_A(0, 1, 0, 0); STAGE_A(0, 1, 1, 0);
    STAGE_B(0, 0, 0, 0); STAGE_B(0, 0, 1, 0); STAGE_B(0, 1, 0, 0); STAGE_B(0, 1, 1, 0);
    STAGE_B(1, 0, 0, 1); STAGE_B(1, 0, 1, 1); STAGE_B(1, 1, 0, 1); STAGE_B(1, 1, 1, 1);
    STAGE_A(1, 0, 0, 1); STAGE_A(1, 0, 1, 1);
    WAIT_VM(6);
    BAR();
    for (int i = 0; i < NI; ++i) {
      const int tt = 2 * i;
      LOAD_B(0, 0); LOAD_B(0, 1); LOAD_A(0, 0, 0);
      STAGE_A(1, 1, 0, tt + 1); STAGE_A(1, 1, 1, tt + 1);
      WAIT_LGKM8();
      BAR(); WAIT_LGKM0();
      MFMA_PH(0, 0);
      BAR();
      LOAD_A(0, 0, 1);
      STAGE_B(0, 0, 0, tt + 2); STAGE_B(0, 1, 0, tt + 2);
      BAR(); WAIT_LGKM0();
      MFMA_PH(0, 1);
      BAR();
      LOAD_A(0, 1, 0);
      STAGE_B(0, 0, 1, tt + 2); STAGE_B(0, 1, 1, tt + 2);
      BAR(); WAIT_LGKM0();
      MFMA_PH(1, 0);
      BAR();
      LOAD_A(0, 1, 1);
      STAGE_A(0, 0, 0, tt + 2); STAGE_A(0, 0, 1, tt + 2);
      WAIT_VM(6);
      BAR(); WAIT_LGKM0();
      MFMA_PH(1, 1);
      BAR();
      LOAD_B(1, 0); LOAD_B(1, 1); LOAD_A(1, 0, 0);
      STAGE_A(0, 1, 0, tt + 2); STAGE_A(0, 1, 1, tt + 2);
      WAIT_LGKM8();
      BAR(); WAIT_LGKM0();
      MFMA_PH(0, 0);
      BAR();
      LOAD_A(1, 0, 1);
      STAGE_B(1, 0, 0, tt + 3); STAGE_B(1, 1, 0, tt + 3);
      BAR(); WAIT_LGKM0();
      MFMA_PH(0, 1);
      BAR();
      LOAD_A(1, 1, 0);
      STAGE_B(1, 0, 1, tt + 3); STAGE_B(1, 1, 1, tt + 3);
      BAR(); WAIT_LGKM0();
      MFMA_PH(1, 0);
      BAR();
      LOAD_A(1, 1, 1);
      STAGE_A(1, 0, 0, tt + 3); STAGE_A(1, 0, 1, tt + 3);
      WAIT_VM(6);
      BAR(); WAIT_LGKM0();
      MFMA_PH(1, 1);
      BAR();
    }
  } else {
    STAGE_A(0, 0, 0, 0); STAGE_A(0, 0, 1, 0);
    STAGE_B(0, 0, 0, 0); STAGE_B(0, 1, 0, 0); STAGE_B(0, 0, 1, 0); STAGE_B(0, 1, 1, 0);
    STAGE_B(1, 0, 0, 1); STAGE_B(1, 1, 0, 1); STAGE_B(1, 0, 1, 1); STAGE_B(1, 1, 1, 1);
    WAIT_VM(4);
    BAR();
    for (int i = 0; i < NI; ++i) {
      const int tt = 2 * i;
      LOAD_B(0, 0); LOAD_B(0, 1); LOAD_A(0, 0, 0);
      STAGE_A(1, 0, 0, tt + 1); STAGE_A(1, 0, 1, tt + 1);
      WAIT_LGKM8();
      BAR(); WAIT_LGKM0();
      MFMA_PH(0, 0);
      BAR();
      LOAD_A(0, 1, 0);
      STAGE_B(0, 0, 0, tt + 2); STAGE_B(0, 1, 0, tt + 2);
      STAGE_B(0, 0, 1, tt + 2); STAGE_B(0, 1, 1, tt + 2);
      WAIT_VM(4);
      BAR(); WAIT_LGKM0();
      MFMA_PH(1, 0);
      BAR();
      LOAD_B(1, 0); LOAD_B(1, 1); LOAD_A(1, 0, 0);
      STAGE_A(0, 0, 0, tt + 2); STAGE_A(0, 0, 1, tt + 2);
      WAIT_LGKM8();
      BAR(); WAIT_LGKM0();
      MFMA_PH(0, 0);
      BAR();
      LOAD_A(1, 1, 0);
      STAGE_B(1, 0, 0, tt + 3); STAGE_B(1, 1, 0, tt + 3);
      STAGE_B(1, 0, 1, tt + 3); STAGE_B(1, 1, 1, tt + 3);
      WAIT_VM(4);
      BAR(); WAIT_LGKM0();
      MFMA_PH(1, 0);
      BAR();
    }
  }

  // ---- epilogue ---- C/D: col=lane&15, row=(lane>>4)*4+reg
  const int rb4 = (lane >> 4) * 4;
  const int wm = (w >> 2) * (BM / 2), wn = (w & 3) * 64;

#pragma unroll
  for (int mf = 0; mf < MF; ++mf) {
#pragma unroll
    for (int nf = 0; nf < 4; ++nf) {
      const int gm0 = m0 + wm + mf * 16 + rb4;
      const int gn = n0 + wn + nf * 16 + fr;
      if constexpr (EPI == EP_GV) {
        if (gn < 1024) {  // G half: plain bf16
#pragma unroll
          for (int r = 0; r < 4; ++r)
            ((ushort*)O0)[(size_t)(gm0 + r) * 1024 + gn] = f2bf(acc[mf][nf][r]);
        } else {  // v' half: transposed write vT[b][d][t]
          const int d = gn - 1024, b = gm0 >> 11, ttp = gm0 & 2047;
          ushort4 w4;
          w4.x = f2bf(acc[mf][nf][0]); w4.y = f2bf(acc[mf][nf][1]);
          w4.z = f2bf(acc[mf][nf][2]); w4.w = f2bf(acc[mf][nf][3]);
          *(ushort4*)&((ushort*)O1)[(size_t)b * LD + (size_t)d * Ll + ttp] = w4;
        }
      } else {
#pragma unroll
        for (int r = 0; r < 4; ++r) {
          const int gm = gm0 + r;
          const size_t idx = (size_t)z * sC + (size_t)gm * ldc + gn;
          const float v = acc[mf][nf][r];
          if constexpr (EPI == EP_UG) {
            const float b = (gn < 2048) ? bias[gn] : bias2[gn - 2048];
            ((ushort*)O0)[idx] = f2bf(v + b);
          } else {  // EP_DOWN
            ((ushort*)O0)[idx] = f2bf(v + bias[gn]);
          }
        }
      }
    }
  }
}

// ---- 4-wave (256-thread) BM=128/BN=128 variant, 64 KiB LDS, 2 blocks/CU ----
// LDS: A dbuf*8192 + kh*4096 + subtile*512 ; B at +16384 same layout.
#define S4A(DBUF, MG, KH, TILE) {                                              \
    const int kt_ = ((TILE) < NTm1 ? (TILE) : NTm1);                           \
    __builtin_amdgcn_global_load_lds(                                          \
      (const __attribute__((address_space(1))) void*)                          \
        (Ag + (size_t)(sRow + (MG)*64) * lda + kt_*64 + (KH)*32 + sCol),       \
      (__attribute__((address_space(3))) void*)                                \
        (lds + (DBUF)*8192 + (KH)*4096 + ((MG)*4 + w4)*512), 16, 0, 0); }

#define S4B(DBUF, NH, KH, TILE) {                                              \
    const int kt_ = ((TILE) < NTm1 ? (TILE) : NTm1);                           \
    __builtin_amdgcn_global_load_lds(                                          \
      (const __attribute__((address_space(1))) void*)                          \
        (Bg + (size_t)(sRow + (NH)*64) * ldb + kt_*64 + (KH)*32 + sCol),       \
      (__attribute__((address_space(3))) void*)                                \
        (lds + 16384 + (DBUF)*8192 + (KH)*4096 + ((NH)*4 + w4)*512), 16, 0, 0); }

#define L4A(DBUF, KS) {                                                        \
  _Pragma("unroll") for (int j_ = 0; j_ < 4; ++j_)                             \
    af[j_] = *(const bf16x8*)&lds[(DBUF)*8192 + (KS)*4096 +                    \
        (aRd + j_)*512 + fr*32 + cph]; }

#define L4B(DBUF, KS) {                                                        \
  _Pragma("unroll") for (int n_ = 0; n_ < 4; ++n_)                             \
    bfr[KS][n_] = *(const bf16x8*)&lds[16384 + (DBUF)*8192 + (KS)*4096 +       \
        (bRd + n_)*512 + fr*32 + cph]; }

#define MFMA4(KS) {                                                            \
  __builtin_amdgcn_s_setprio(1);                                               \
  _Pragma("unroll") for (int j_ = 0; j_ < 4; ++j_)                             \
  _Pragma("unroll") for (int n_ = 0; n_ < 4; ++n_)                             \
    acc[j_][n_] = __builtin_amdgcn_mfma_f32_16x16x32_bf16(                     \
        af[j_], bfr[KS][n_], acc[j_][n_], 0, 0, 0);                            \
  __builtin_amdgcn_s_setprio(0); }

template <int EPI>  // EP_DECAY or EP_YO
__global__ __launch_bounds__(256, 2) void gemm4_k(
    const ushort* __restrict__ A, const ushort* __restrict__ Bm,
    void* __restrict__ O0, const float* __restrict__ xres,
    const float* __restrict__ decayp,
    int K, int lda, int ldb, int ldc, long sA, long sB, long sC) {
  __shared__ ushort lds[32768];  // 64 KiB

  const int t = threadIdx.x;
  const int lane = t & 63;
  const int w4 = t >> 6;

  int z, m0, n0;
  if constexpr (EPI == EP_YO) {
    // grid (8,64) flat; id and id+256 -> complementary m-tiles (i, 15-i)
    const int id = blockIdx.y * gridDim.x + blockIdx.x;
    const int half = id >> 8;
    const int u = id & 255;
    const int nt = u & 7;
    const int rem = u >> 3;  // 0..31
    z = rem >> 3;
    const int i8 = rem & 7;
    const int mt = half ? (15 - i8) : i8;
    m0 = mt * 128;
    n0 = nt * 128;
  } else {  // EP_DECAY: grid (16,16,4), XCD swizzle + tril filter
    z = blockIdx.z;
    const int gx = gridDim.x;
    const int nwg = gx * gridDim.y;
    const int id = blockIdx.y * gx + blockIdx.x;
    const int chunk = nwg >> 3;
    const int swz = (id & 7) * chunk + (id >> 3);
    m0 = (swz / gx) * 128;
    n0 = (swz % gx) * 128;
    if (n0 > m0) return;  // above diagonal: never read by YO (K-clamp)
  }

  const ushort* Ag = A + (size_t)z * sA + (size_t)m0 * lda;
  const ushort* Bg = Bm + (size_t)z * sB + (size_t)n0 * ldb;

  int Kend = K;
  if constexpr (EPI == EP_YO) Kend = m0 + 128;
  const int NT = Kend >> 6;
  const int NTm1 = NT - 1;
  const int NI = NT >> 1;

  const int lp = lane ^ (((lane >> 5) & 1) << 1);
  const int sRow = w4 * 16 + (lp >> 2);
  const int sCol = (lp & 3) * 8;
  const int fr = lane & 15;
  const int kg = (lane >> 4) * 8;
  const int cph = kg ^ (((fr >> 3) & 1) << 4);
  const int aRd = (w4 >> 1) * 4;  // wm = (w4>>1)*64
  const int bRd = (w4 & 1) * 4;   // wn = (w4&1)*64

  f32x4 acc[4][4] = {};
  bf16x8 af[4], bfr[2][4];

  // prologue: A0(4) + B0(4) + B1(4); vmcnt(4) leaves B1 in flight
  S4A(0, 0, 0, 0); S4A(0, 1, 0, 0); S4A(0, 0, 1, 0); S4A(0, 1, 1, 0);
  S4B(0, 0, 0, 0); S4B(0, 1, 0, 0); S4B(0, 0, 1, 0); S4B(0, 1, 1, 0);
  S4B(1, 0, 0, 1); S4B(1, 1, 0, 1); S4B(1, 0, 1, 1); S4B(1, 1, 1, 1);
  WAIT_VM(4);
  BAR();
  for (int i = 0; i < NI; ++i) {
    const int tt = 2 * i;
    // ph1 (tile tt, buf0, ks0) | stage A[tt+1] -> buf1
    L4B(0, 0); L4B(0, 1); L4A(0, 0);
    S4A(1, 0, 0, tt + 1); S4A(1, 1, 0, tt + 1);
    S4A(1, 0, 1, tt + 1); S4A(1, 1, 1, tt + 1);
    WAIT_LGKM8();
    BAR(); WAIT_LGKM0();
    MFMA4(0);
    BAR();
    // ph2 (ks1) | stage B[tt+2] -> buf0; vmcnt(4) lands A[tt+1],B[tt+1]
    L4A(0, 1);
    S4B(0, 0, 0, tt + 2); S4B(0, 1, 0, tt + 2);
    S4B(0, 0, 1, tt + 2); S4B(0, 1, 1, tt + 2);
    WAIT_VM(4);
    BAR(); WAIT_LGKM0();
    MFMA4(1);
    BAR();
    // ph3 (tile tt+1, buf1, ks0) | stage A[tt+2] -> buf0
    L4B(1, 0); L4B(1, 1); L4A(1, 0);
    S4A(0, 0, 0, tt + 2); S4A(0, 1, 0, tt + 2);
    S4A(0, 0, 1, tt + 2); S4A(0, 1, 1, tt + 2);
    WAIT_LGKM8();
    BAR(); WAIT_LGKM0();
    MFMA4(0);
    BAR();
    // ph4 (ks1) | stage B[tt+3] -> buf1; vmcnt(4) lands A[tt+2],B[tt+2]
    L4A(1, 1);
    S4B(1, 0, 0, tt + 3); S4B(1, 1, 0, tt + 3);
    S4B(1, 0, 1, tt + 3); S4B(1, 1, 1, tt + 3);
    WAIT_VM(4);
    BAR(); WAIT_LGKM0();
    MFMA4(1);
    BAR();
  }

  // ---- epilogue ----
  const int rb4 = (lane >> 4) * 4;
  const int wm = (w4 >> 1) * 64, wn = (w4 & 1) * 64;
  float logd = 0.f;
  if constexpr (EPI == EP_DECAY) logd = __logf(decayp[0]);

#pragma unroll
  for (int mf = 0; mf < 4; ++mf) {
#pragma unroll
    for (int nf = 0; nf < 4; ++nf) {
      const int gm0 = m0 + wm + mf * 16 + rb4;
      const int gn = n0 + wn + nf * 16 + fr;
#pragma unroll
      for (int r = 0; r < 4; ++r) {
        const int gm = gm0 + r;
        const size_t idx = (size_t)z * sC + (size_t)gm * ldc + gn;
        const float v = acc[mf][nf][r];
        if constexpr (EPI == EP_DECAY) {
          ((ushort*)O0)[idx] =
              (gn <= gm) ? f2bf(v * __expf((float)(gm - gn) * logd)) : (ushort)0;
        } else {  // EP_YO: out = x + S@v'
          ((float*)O0)[idx] = v + xres[idx];
        }
      }
    }
  }
}

// One launch for all prep: 4 transposes, 3 straight converts, conv pack,
// rmsnorm.
__global__ __launch_bounds__(256) void prep_k(
    const float* __restrict__ up_w, const float* __restrict__ gate_w,
    const float* __restrict__ down_w, const float* __restrict__ wq,
    const float* __restrict__ wk, const float* __restrict__ wv,
    const float* __restrict__ wo, const float* __restrict__ conv_w,
    const float* __restrict__ x, const float* __restrict__ norm_w,
    ushort* __restrict__ ugw, ushort* __restrict__ down_wT,
    ushort* __restrict__ wq_bf, ushort* __restrict__ wk_bf,
    ushort* __restrict__ wv_bf, ushort* __restrict__ wo_T,
    ushort* __restrict__ cwT, ushort* __restrict__ nrm) {
  const int bid = blockIdx.x;
  const int t = threadIdx.x;
  if (bid < 7168) {  // transposes: fp32 [R][C] -> bf16 [C][R]
    const float* src; ushort* dst; int R, C, idx;
    if (bid < 2048)      { src = up_w;   dst = ugw;               R = 1024; C = 2048; idx = bid; }
    else if (bid < 4096) { src = gate_w; dst = ugw + 2048 * 1024; R = 1024; C = 2048; idx = bid - 2048; }
    else if (bid < 6144) { src = down_w; dst = down_wT;           R = 2048; C = 1024; idx = bid - 4096; }
    else                 { src = wo;     dst = wo_T;              R = 1024; C = 1024; idx = bid - 6144; }
    __shared__ float tile[32][33];
    const int tx = t & 31, ty = t >> 5;
    const int tilesx = C >> 5;
    const int c0 = (idx % tilesx) * 32, r0 = (idx / tilesx) * 32;
#pragma unroll
    for (int i = 0; i < 4; ++i)
      tile[ty + i * 8][tx] = src[(size_t)(r0 + ty + i * 8) * C + c0 + tx];
    __syncthreads();
#pragma unroll
    for (int i = 0; i < 4; ++i)
      dst[(size_t)(c0 + ty + i * 8) * R + r0 + tx] = f2bf(tile[tx][ty + i * 8]);
  } else if (bid < 10240) {  // straight converts wq/wk/wv
    const int seg = (bid - 7168) >> 10;
    const int idx = (bid - 7168) & 1023;
    const float* src = (seg == 0) ? wq : (seg == 1) ? wk : wv;
    ushort* dst = (seg == 0) ? wq_bf : (seg == 1) ? wk_bf : wv_bf;
    const size_t e = (size_t)idx * 1024 + t * 4;
    const float4 v = *(const float4*)(src + e);
    ushort4 r;
    r.x = f2bf(v.x); r.y = f2bf(v.y); r.z = f2bf(v.z); r.w = f2bf(v.w);
    *(ushort4*)(dst + e) = r;
  } else if (bid < 10248) {  // conv_w [DI][4] -> cwT [4][DI]
    const int c = (bid - 10240) * 256 + t;
    const float4 v = *(const float4*)(conv_w + c * 4);
    cwT[0 * DIc + c] = f2bf(v.x);
    cwT[1 * DIc + c] = f2bf(v.y);
    cwT[2 * DIc + c] = f2bf(v.z);
    cwT[3 * DIc + c] = f2bf(v.w);
  } else {  // rmsnorm rows
    const int row = bid - 10248;
    const float* xr = x + (size_t)row * Dd;
    const float4 v = *(const float4*)(xr + t * 4);
    float ss = v.x * v.x + v.y * v.y + v.z * v.z + v.w * v.w;
#pragma unroll
    for (int m = 32; m; m >>= 1) ss += __shfl_xor(ss, m);
    __shared__ float red[4];
    if ((t & 63) == 0) red[t >> 6] = ss;
    __syncthreads();
    const float total = red[0] + red[1] + red[2] + red[3];
    const float rs = rsqrtf(total * (1.f / (float)Dd) + 1e-6f);
    const float4 wt = *(const float4*)(norm_w + t * 4);
    ushort4 r;
    r.x = f2bf(v.x * rs * wt.x); r.y = f2bf(v.y * rs * wt.y);
    r.z = f2bf(v.z * rs * wt.z); r.w = f2bf(v.w * rs * wt.w);
    *(ushort4*)(nrm + (size_t)row * Dd + t * 4) = r;
  }
}

// bid<128: 256-thread m97-style 128x128 weight-product GEMM blocks
//   (WsT = wk@wq^T, Wv2T = wo^T@wv^T; inputs prepped by prep_k).
// bid>=128: conv: combined = silu(conv(up)+cb)*silu(gate), 8ch x 8t/thread.
__global__ __launch_bounds__(256) void conv_gate_k(
    const ushort* __restrict__ ug, const ushort* __restrict__ cwT,
    const float* __restrict__ cb, ushort* __restrict__ o,
    const ushort* __restrict__ wk_bf, const ushort* __restrict__ wq_bf,
    const ushort* __restrict__ wo_T, const ushort* __restrict__ wv_bf,
    ushort* __restrict__ WsT, ushort* __restrict__ Wv2T) {
  const int bid = blockIdx.x;
  const int t = threadIdx.x;
  if (bid < 128) {
    __shared__ ushort lds[8192];
    ushort* As = lds;
    ushort* Bs = lds + 4096;
    const int oo = bid >> 6, lid = bid & 63;
    const int m0 = (lid >> 3) * 128, n0 = (lid & 7) * 128;
    const ushort* A = (oo ? wo_T : wk_bf) + (size_t)m0 * 1024;
    const ushort* B = (oo ? wv_bf : wq_bf) + (size_t)n0 * 1024;
    ushort* C = oo ? Wv2T : WsT;
    const int lane = t & 63, wave = t >> 6;
    const int wm = (wave >> 1) * 64, wn = (wave & 1) * 64;
    const int fr = lane & 15, kg = (lane >> 4) * 8;
    const int srow0 = wave * 16 + (lane >> 2), scol = (lane & 3) * 8;
    f32x4 acc[4][4] = {};
    for (int k0 = 0; k0 < 1024; k0 += 32) {
#pragma unroll
      for (int p = 0; p < 2; ++p) {
        __builtin_amdgcn_global_load_lds(
            (const __attribute__((address_space(1))) void*)
                (A + (size_t)(srow0 + p * 64) * 1024 + k0 + scol),
            (__attribute__((address_space(3))) void*)(As + (p * 4 + wave) * 512),
            16, 0, 0);
        __builtin_amdgcn_global_load_lds(
            (const __attribute__((address_space(1))) void*)
                (B + (size_t)(srow0 + p * 64) * 1024 + k0 + scol),
            (__attribute__((address_space(3))) void*)(Bs + (p * 4 + wave) * 512),
            16, 0, 0);
      }
      __syncthreads();
      bf16x8 af[4], bv[4];
#pragma unroll
      for (int i = 0; i < 4; ++i) {
        af[i] = *(const bf16x8*)&As[(wm + i * 16 + fr) * 32 + kg];
        bv[i] = *(const bf16x8*)&Bs[(wn + i * 16 + fr) * 32 + kg];
      }
#pragma unroll
      for (int mi = 0; mi < 4; ++mi)
#pragma unroll
        for (int ni = 0; ni < 4; ++ni)
          acc[mi][ni] = __builtin_amdgcn_mfma_f32_16x16x32_bf16(
              af[mi], bv[ni], acc[mi][ni], 0, 0, 0);
      __syncthreads();
    }
    const int rb = (lane >> 4) * 4;
#pragma unroll
    for (int mi = 0; mi < 4; ++mi)
#pragma unroll
      for (int ni = 0; ni < 4; ++ni)
#pragma unroll
        for (int r = 0; r < 4; ++r)
          C[(size_t)(m0 + wm + mi * 16 + rb + r) * 1024 + n0 + wn + ni * 16 + fr] =
              f2bf(acc[mi][ni][r]);
    return;
  }

  const int cbid = bid - 128;
  const int cg = t & 31;
  const int ts = t >> 5;
  const int cblk = cbid & 7;
  const int rblk = cbid >> 3;
  const int c = cblk * 256 + cg * 8;
  const int row0 = rblk * 64 + ts * 8;

  u16x8 w[4];
#pragma unroll
  for (int k = 0; k < 4; ++k) w[k] = *(const u16x8*)&cwT[k * DIc + c];
  float wb[8];
  *(float4*)&wb[0] = *(const float4*)(cb + c);
  *(float4*)&wb[4] = *(const float4*)(cb + c + 4);

  u16x8 h3, h2, h1;
  if ((row0 & (Ll - 1)) == 0) {
    h3 = (u16x8){}; h2 = (u16x8){}; h1 = (u16x8){};
  } else {
    h3 = *(const u16x8*)&ug[(size_t)(row0 - 3) * 4096 + c];
    h2 = *(const u16x8*)&ug[(size_t)(row0 - 2) * 4096 + c];
    h1 = *(const u16x8*)&ug[(size_t)(row0 - 1) * 4096 + c];
  }

#pragma unroll
  for (int i = 0; i < 8; ++i) {
    const size_t rbase = (size_t)(row0 + i) * 4096;
    const u16x8 h0 = *(const u16x8*)&ug[rbase + c];
    const u16x8 g  = *(const u16x8*)&ug[rbase + 2048 + c];
    u16x8 ov;
#pragma unroll
    for (int j = 0; j < 8; ++j) {
      float acc = wb[j];
      acc += bf2f(w[0][j]) * bf2f(h3[j]);
      acc += bf2f(w[1][j]) * bf2f(h2[j]);
      acc += bf2f(w[2][j]) * bf2f(h1[j]);
      acc += bf2f(w[3][j]) * bf2f(h0[j]);
      ov[j] = f2bf(silu(acc) * silu(bf2f(g[j])));
    }
    *(u16x8*)&o[(size_t)(row0 + i) * DIc + c] = ov;
    h3 = h2; h2 = h1; h1 = h0;
  }
}

extern "C" void kernel_launch(void* const* d_in, const int* in_sizes, int n_in,
                              void* d_out, int out_size, void* d_ws,
                              size_t ws_size, hipStream_t stream) {
  const float* x      = (const float*)d_in[0];
  const float* norm_w = (const float*)d_in[1];
  const float* up_w   = (const float*)d_in[2];
  const float* up_b   = (const float*)d_in[3];
  const float* gate_w = (const float*)d_in[4];
  const float* gate_b = (const float*)d_in[5];
  const float* down_w = (const float*)d_in[6];
  const float* down_b = (const float*)d_in[7];
  const float* conv_w = (const float*)d_in[8];
  const float* conv_b = (const float*)d_in[9];
  const float* wq     = (const float*)d_in[10];
  const float* wk     = (const float*)d_in[11];
  const float* wv     = (const float*)d_in[12];
  const float* wo     = (const float*)d_in[13];
  const float* decay  = (const float*)d_in[14];
  float* out = (float*)d_out;
  char* w8 = (char*)d_ws;

  const size_t MiB = 1u << 20;
  ushort* nrm      = (ushort*)(w8 + 0 * MiB);    // 16: normed, later D (down-out)
  ushort* ug       = (ushort*)(w8 + 16 * MiB);   // 64: up|gate [8192][4096]
  ushort* S        = (ushort*)(w8 + 16 * MiB);   // 32 (aliases ug; disjoint life)
  ushort* combined = (ushort*)(w8 + 80 * MiB);   // 32
  ushort* G        = (ushort*)(w8 + 112 * MiB);  // 16: G = D @ W_qk
  ushort* vT       = (ushort*)(w8 + 144 * MiB);  // 16: v'T[b][d][t]
  ushort* ugw      = (ushort*)(w8 + 176 * MiB);  // 8: [4096][1024]
  ushort* down_wT  = (ushort*)(w8 + 184 * MiB);  // 4: [1024][2048]
  ushort* wq_bf    = (ushort*)(w8 + 188 * MiB);  // 2 (raw row-major bf16)
  ushort* wk_bf    = (ushort*)(w8 + 190 * MiB);  // 2
  ushort* wv_bf    = (ushort*)(w8 + 192 * MiB);  // 2
  ushort* wo_T     = (ushort*)(w8 + 194 * MiB);  // 2
  ushort* WsT      = (ushort*)(w8 + 196 * MiB);  // 2: wk @ wq^T
  ushort* Wv2T     = (ushort*)(w8 + 198 * MiB);  // 2: wo^T @ wv^T (contig w/ WsT)
  ushort* cwT      = (ushort*)(w8 + 200 * MiB);  // 16 KiB

  prep_k<<<18440, 256, 0, stream>>>(up_w, gate_w, down_w, wq, wk, wv, wo,
                                    conv_w, x, norm_w,
                                    ugw, down_wT, wq_bf, wk_bf, wv_bf, wo_T,
                                    cwT, nrm);

  // ug = normed @ [up_w|gate_w] + biases  (512 blocks = 2 rounds)
  gemm8_k<EP_UG, 256><<<dim3(16, 32), 512, 0, stream>>>(
      nrm, ugw, ug, up_b, gate_b,
      1024, 1024, 1024, 4096, 0, 0, 0, nullptr);

  // 128 weight-product GEMM blocks + 1024 conv blocks (backfill)
  conv_gate_k<<<1152, 256, 0, stream>>>(ug, cwT, conv_b, combined,
                                        wk_bf, wq_bf, wo_T, wv_bf, WsT, Wv2T);

  // D = combined @ down_w + b  (256 blocks = 1 round)
  gemm8_k<EP_DOWN, 128><<<dim3(4, 64), 512, 0, stream>>>(
      combined, down_wT, nrm, down_b, nullptr,
      2048, 2048, 2048, 1024, 0, 0, 0, nullptr);

  // [G | v'] = D @ [WsT | Wv2T]^T  (256 blocks = 1 round, BM=256)
  gemm8_k<EP_GV, 256><<<dim3(8, 32), 512, 0, stream>>>(
      nrm, WsT, G, nullptr, nullptr,
      1024, 1024, 1024, 1024, 0, 0, 0, vT);

  // S = tril(G @ D^T) * d^(t-s)  (4-wave, 544 active blocks, 2/CU)
  gemm4_k<EP_DECAY><<<dim3(16, 16, Bb), 256, 0, stream>>>(
      G, nrm, S, nullptr, decay,
      1024, 1024, 1024, 2048, LD, LD, (long)Ll * Ll);

  // out = x + S @ v'  (4-wave, 512 blocks, complementary-K pairing)
  gemm4_k<EP_YO><<<dim3(8, 64), 256, 0, stream>>>(
      S, vT, out, x, nullptr,
      0, 2048, 2048, 1024, (long)Ll * Ll, LD, LD);
}